// Round 4
// baseline (519.119 us; speedup 1.0000x reference)
//
#include <hip/hip_runtime.h>

typedef unsigned short ushort_t;
typedef __attribute__((ext_vector_type(8))) short short8;
typedef __attribute__((ext_vector_type(4))) float floatx4;

// ---------- helpers ----------
__device__ __forceinline__ ushort_t f2bf(float f) {
    unsigned u = __float_as_uint(f);
    return (ushort_t)((u + 0x7fffu + ((u >> 16) & 1u)) >> 16);
}
__device__ __forceinline__ void gll16(const void* g, void* l) {
    __builtin_amdgcn_global_load_lds(
        (const __attribute__((address_space(1))) unsigned int*)g,
        (__attribute__((address_space(3))) unsigned int*)l, 16, 0, 0);
}
#if __has_builtin(__builtin_amdgcn_exp2f)
#define EXP2f(x) __builtin_amdgcn_exp2f(x)
#else
#define EXP2f(x) exp2f(x)
#endif

// ---------- fused: cast x -> bf16  +  LDS-tiled transpose+cast of wq/wk ----------
__global__ __launch_bounds__(256) void prep_tr_kernel(
    const float* __restrict__ x, ushort_t* __restrict__ xb,
    const float* __restrict__ wq, const float* __restrict__ wk,
    ushort_t* __restrict__ wqT, ushort_t* __restrict__ wkT)
{
    __shared__ float t[64][65];
    const int bid = blockIdx.x;
    const int tid = threadIdx.x;
    if (bid < 8192) {
        size_t i = ((size_t)bid * 256 + tid) * 8;
        float4 v0 = *(const float4*)(x + i);
        float4 v1 = *(const float4*)(x + i + 4);
        uint4 o;
        o.x = (unsigned)f2bf(v0.x) | ((unsigned)f2bf(v0.y) << 16);
        o.y = (unsigned)f2bf(v0.z) | ((unsigned)f2bf(v0.w) << 16);
        o.z = (unsigned)f2bf(v1.x) | ((unsigned)f2bf(v1.y) << 16);
        o.w = (unsigned)f2bf(v1.z) | ((unsigned)f2bf(v1.w) << 16);
        *(uint4*)(xb + i) = o;
        return;
    }
    const int b2 = bid - 8192;               // 0..511
    const int bx = b2 & 15, by = (b2 >> 4) & 15, bz = b2 >> 8;
    const float* src = bz ? wk : wq;
    ushort_t* dst = bz ? wkT : wqT;
    const int k0 = bx * 64, n0 = by * 64;
    const int rr = tid >> 4, cc = (tid & 15) * 4;
#pragma unroll
    for (int p = 0; p < 4; ++p) {
        float4 v = *(const float4*)(src + (size_t)(k0 + p * 16 + rr) * 1024 + n0 + cc);
        t[p * 16 + rr][cc + 0] = v.x;
        t[p * 16 + rr][cc + 1] = v.y;
        t[p * 16 + rr][cc + 2] = v.z;
        t[p * 16 + rr][cc + 3] = v.w;
    }
    __syncthreads();
#pragma unroll
    for (int p = 0; p < 4; ++p) {
        int nl = p * 16 + rr;
        uint2 o;
        o.x = (unsigned)f2bf(t[cc + 0][nl]) | ((unsigned)f2bf(t[cc + 1][nl]) << 16);
        o.y = (unsigned)f2bf(t[cc + 2][nl]) | ((unsigned)f2bf(t[cc + 3][nl]) << 16);
        *(uint2*)(dst + (size_t)(n0 + nl) * 1024 + k0 + cc) = o;
    }
}

// ---------- MFMA bf16 GEMM: Q+K fused, 4-deep pipeline, counted vmcnt ----------
// Replaces per-kt __syncthreads (vmcnt(0) drain) with: s_waitcnt vmcnt(6) +
// raw s_barrier. 4 LDS buffers rotate; stages kt+1,kt+2 stay in flight across
// the barrier (T4 mechanism). Race-safety: barrier(kt) implies (a) every
// thread's stage-kt loads landed (each waited own vmcnt), (b) every wave's
// compute(kt-1) ds_reads consumed (lgkm waits precede barrier) -> rewriting
// buf[(kt+3)&3] == buf[(kt-1)&3] is safe. Source-side XOR swizzle unchanged.
__global__ __launch_bounds__(512, 2) void gemm_qk_kernel(
    const ushort_t* __restrict__ xb, const ushort_t* __restrict__ wqT, const ushort_t* __restrict__ wkT,
    const float* __restrict__ bq, const float* __restrict__ bk,
    ushort_t* __restrict__ Qb, ushort_t* __restrict__ Kb)
{
    const int bm = blockIdx.x;          // 128 M-tiles of 128
    const int bn = blockIdx.y;          // 8 N-tiles of 128

    __shared__ ushort_t a_lds[4][128 * 32];    // 4 x 8 KB
    __shared__ ushort_t q_lds[4][128 * 32];
    __shared__ ushort_t k_lds[4][128 * 32];

    const int tid = threadIdx.x;
    const int lane = tid & 63;
    const int wave = tid >> 6;          // 0..7
    const int wmat = wave >> 2;         // 0=Q, 1=K
    const int wr = (wave >> 1) & 1, wc = wave & 1;
    const int l16 = lane & 15, quad = lane >> 4;
    const int qs = quad ^ ((l16 >> 1) & 3);   // swizzled chunk for fragment reads

    floatx4 acc[4][4];
    const floatx4 zero4 = {0.f, 0.f, 0.f, 0.f};
#pragma unroll
    for (int i = 0; i < 4; ++i)
#pragma unroll
        for (int j = 0; j < 4; ++j) acc[i][j] = zero4;

    // staging: thread t covers row t>>2, 16B-chunk t&3 of a 128x32 tile;
    // source chunk pre-swizzled with (row>>1)&3 == (t>>3)&3 (involution).
    const int srow = tid >> 2;
    const int skof = ((tid & 3) ^ ((tid >> 3) & 3)) * 8;
    const ushort_t* gA = xb + (size_t)(bm * 128 + srow) * 1024 + skof;
    const ushort_t* gQ = wqT + (size_t)(bn * 128 + srow) * 1024 + skof;
    const ushort_t* gK = wkT + (size_t)(bn * 128 + srow) * 1024 + skof;

    auto issue = [&](int s) {           // stage s -> buffer s&3, 3 gll16/thread
        const int buf = s & 3;
        const int k0 = s * 32;
        gll16(gA + k0, &a_lds[buf][wave * 512]);
        gll16(gQ + k0, &q_lds[buf][wave * 512]);
        gll16(gK + k0, &k_lds[buf][wave * 512]);
    };

    auto compute = [&](int s) {
        const int buf = s & 3;
        const ushort_t* la = a_lds[buf];
        const ushort_t* lb = wmat ? k_lds[buf] : q_lds[buf];
        short8 afr[4], bfr[4];
#pragma unroll
        for (int mi = 0; mi < 4; ++mi)
            afr[mi] = *(const short8*)&la[(wr * 64 + mi * 16 + l16) * 32 + qs * 8];
#pragma unroll
        for (int ni = 0; ni < 4; ++ni)
            bfr[ni] = *(const short8*)&lb[(wc * 64 + ni * 16 + l16) * 32 + qs * 8];
#pragma unroll
        for (int mi = 0; mi < 4; ++mi)
#pragma unroll
            for (int ni = 0; ni < 4; ++ni)
                acc[mi][ni] = __builtin_amdgcn_mfma_f32_16x16x32_bf16(afr[mi], bfr[ni], acc[mi][ni], 0, 0, 0);
    };

    issue(0); issue(1); issue(2);
#pragma unroll 4
    for (int kt = 0; kt < 29; ++kt) {
        asm volatile("s_waitcnt vmcnt(6)" ::: "memory");
        __builtin_amdgcn_s_barrier();
        __builtin_amdgcn_sched_barrier(0);
        issue(kt + 3);
        compute(kt);
    }
    asm volatile("s_waitcnt vmcnt(6)" ::: "memory");
    __builtin_amdgcn_s_barrier();
    __builtin_amdgcn_sched_barrier(0);
    compute(29);
    asm volatile("s_waitcnt vmcnt(3)" ::: "memory");
    __builtin_amdgcn_s_barrier();
    __builtin_amdgcn_sched_barrier(0);
    compute(30);
    asm volatile("s_waitcnt vmcnt(0)" ::: "memory");
    __builtin_amdgcn_s_barrier();
    __builtin_amdgcn_sched_barrier(0);
    compute(31);

    // epilogue (per-wave matrix select; single base + immediate offsets)
    ushort_t* Out = wmat ? Kb : Qb;
    const float* bias = wmat ? bk : bq;
    // Q postscale = log2(e)/sqrt(128): attention uses exp2 directly.
    const float postscale = wmat ? 1.0f : 0.12751744900508692f;

    const int bq_ = bm >> 3;                               // batch index (constant)
    const int sb = (bm & 7) * 128 + wr * 64 + quad * 4;    // seq base (+ mi*16 + r)
    const int dc = wc * 64 + l16;                          // head-dim base (+ ni*16)
    float bp[4];
#pragma unroll
    for (int ni = 0; ni < 4; ++ni) bp[ni] = bias[bn * 128 + dc + ni * 16] * postscale;
    ushort_t* ob = Out + ((size_t)(bq_ * 8 + bn) * 1024 + sb) * 128 + dc;
#pragma unroll
    for (int mi = 0; mi < 4; ++mi)
#pragma unroll
        for (int ni = 0; ni < 4; ++ni) {
            ushort_t* p = ob + mi * 2048 + ni * 16;
#pragma unroll
            for (int r = 0; r < 4; ++r)
                p[r * 128] = f2bf(fmaf(acc[mi][ni][r], postscale, bp[ni]));
        }
}

// ---------- attention column sums via MFMA, QBLK=256, 8 waves share K-tile ----------
// Per-wave math identical to the verified 4-wave/QBLK=128 kernel; the K-tile
// staging (2 gll16/thread) and geometry widened so each staged tile feeds 2x
// the MFMA. Q pre-scaled by log2e/sqrt(dk) -> raw exp2.
__global__ __launch_bounds__(512, 4) void attn_mfma_kernel(
    const ushort_t* __restrict__ Qb,   // [bh][1024][128] bf16 (exp2-scaled)
    const ushort_t* __restrict__ Kb,   // [bh][1024][128] bf16
    float* __restrict__ wout)          // [bh][1024], zero-init
{
    const int bh = blockIdx.x;         // 128
    const int qt = blockIdx.y;         // 4 q-tiles of 256 rows
    __shared__ ushort_t ks[2][64 * 128]; // 2 x 16 KB, XOR-swizzled 16B granules

    const int tid = threadIdx.x;
    const int wave = tid >> 6, lane = tid & 63;
    const int l16 = lane & 15, quad = lane >> 4;

    const ushort_t* Ksrc = Kb + (size_t)bh * 1024 * 128;

    // staging: call c in {0,1}; thread t covers row c*32 + (t>>4), granule t&15;
    // content granule g = (t&15) ^ (row&15) (involution, matches read side).
    int srcoff[2];
#pragma unroll
    for (int c = 0; c < 2; ++c) {
        int r = c * 32 + (tid >> 4);
        int g = (tid & 15) ^ (r & 15);
        srcoff[c] = r * 128 + g * 8;
    }

    auto issue = [&](int buf, int kt) {
        const ushort_t* src = Ksrc + (size_t)kt * 8192;
#pragma unroll
        for (int c = 0; c < 2; ++c)
            gll16(src + srcoff[c], &ks[buf][c * 4096 + wave * 512]);
    };

    // Q fragments, kept in registers for both passes (wave owns 32 Q-rows)
    short8 aq[2][4];
    {
        const ushort_t* qsrc = Qb + ((size_t)bh * 1024 + qt * 256 + wave * 32) * 128;
#pragma unroll
        for (int mi = 0; mi < 2; ++mi)
#pragma unroll
            for (int ksp = 0; ksp < 4; ++ksp)
                aq[mi][ksp] = *(const short8*)(qsrc + (size_t)(mi * 16 + l16) * 128 + ksp * 32 + quad * 8);
    }

    const floatx4 zero4 = {0.f, 0.f, 0.f, 0.f};
    float lsum[2][4];
#pragma unroll
    for (int mi = 0; mi < 2; ++mi)
#pragma unroll
        for (int r = 0; r < 4; ++r) lsum[mi][r] = 0.f;

    issue(0, 0);

    // ---- pass 1: row sums of exp2(s) ----
    for (int kt = 0; kt < 16; ++kt) {
        __syncthreads();
        if (kt < 15) issue((kt + 1) & 1, kt + 1);
        const ushort_t* kbuf = ks[kt & 1];
        floatx4 acc[2][4];
#pragma unroll
        for (int mi = 0; mi < 2; ++mi)
#pragma unroll
            for (int ni = 0; ni < 4; ++ni) acc[mi][ni] = zero4;
#pragma unroll
        for (int ksp = 0; ksp < 4; ++ksp) {
            short8 bk[4];
#pragma unroll
            for (int ni = 0; ni < 4; ++ni) {
                int n = ni * 16 + l16;
                int gs = (ksp * 4 + quad) ^ (n & 15);
                bk[ni] = *(const short8*)&kbuf[n * 128 + gs * 8];
            }
#pragma unroll
            for (int mi = 0; mi < 2; ++mi)
#pragma unroll
                for (int ni = 0; ni < 4; ++ni)
                    acc[mi][ni] = __builtin_amdgcn_mfma_f32_16x16x32_bf16(aq[mi][ksp], bk[ni], acc[mi][ni], 0, 0, 0);
        }
#pragma unroll
        for (int mi = 0; mi < 2; ++mi)
#pragma unroll
            for (int r = 0; r < 4; ++r) {
                float s = 0.f;
#pragma unroll
                for (int ni = 0; ni < 4; ++ni) s += EXP2f(acc[mi][ni][r]);
                lsum[mi][r] += s;
            }
    }

    issue(0, 0);    // prefetch pass-2 tile 0 (buf0's last readers finished before kt=15's barrier)

    float invl[2][4];
#pragma unroll
    for (int mi = 0; mi < 2; ++mi)
#pragma unroll
        for (int r = 0; r < 4; ++r) {
            float s = lsum[mi][r];
#pragma unroll
            for (int off = 1; off < 16; off <<= 1) s += __shfl_xor(s, off, 16);
            invl[mi][r] = 1.f / s;
        }

    // ---- pass 2: column sums of exp2(s)/l ----
    for (int kt = 0; kt < 16; ++kt) {
        __syncthreads();
        if (kt < 15) issue((kt + 1) & 1, kt + 1);
        const ushort_t* kbuf = ks[kt & 1];
        floatx4 acc[2][4];
#pragma unroll
        for (int mi = 0; mi < 2; ++mi)
#pragma unroll
            for (int ni = 0; ni < 4; ++ni) acc[mi][ni] = zero4;
#pragma unroll
        for (int ksp = 0; ksp < 4; ++ksp) {
            short8 bk[4];
#pragma unroll
            for (int ni = 0; ni < 4; ++ni) {
                int n = ni * 16 + l16;
                int gs = (ksp * 4 + quad) ^ (n & 15);
                bk[ni] = *(const short8*)&kbuf[n * 128 + gs * 8];
            }
#pragma unroll
            for (int mi = 0; mi < 2; ++mi)
#pragma unroll
                for (int ni = 0; ni < 4; ++ni)
                    acc[mi][ni] = __builtin_amdgcn_mfma_f32_16x16x32_bf16(aq[mi][ksp], bk[ni], acc[mi][ni], 0, 0, 0);
        }
#pragma unroll
        for (int ni = 0; ni < 4; ++ni) {
            float s = 0.f;
#pragma unroll
            for (int mi = 0; mi < 2; ++mi)
#pragma unroll
                for (int r = 0; r < 4; ++r)
                    s += EXP2f(acc[mi][ni][r]) * invl[mi][r];
            s += __shfl_xor(s, 16, 64);
            s += __shfl_xor(s, 32, 64);
            if (quad == 0) atomicAdd(&wout[bh * 1024 + kt * 64 + ni * 16 + l16], s);
        }
    }
}

// ---------- u[b,h,:] = sum_k w[b,h,k] * xb[b,k,:]  (bf16 x) ----------
__global__ __launch_bounds__(256) void u_kernel(const ushort_t* __restrict__ xb,
                                                const float* __restrict__ w,
                                                float* __restrict__ u)
{
    const int b = blockIdx.x, kc = blockIdx.y;
    const int c4 = threadIdx.x;
    const ushort_t* Xp = xb + ((size_t)(b * 1024 + kc * 64)) * 1024 + c4 * 4;
    float4 acc[8];
#pragma unroll
    for (int h = 0; h < 8; ++h) acc[h] = make_float4(0.f, 0.f, 0.f, 0.f);
    const float* wb = w + b * 8 * 1024 + kc * 64;
    for (int k = 0; k < 64; ++k) {
        uint2 uv = *(const uint2*)(Xp + (size_t)k * 1024);
        float x0 = __uint_as_float(uv.x << 16);
        float x1 = __uint_as_float(uv.x & 0xffff0000u);
        float x2 = __uint_as_float(uv.y << 16);
        float x3 = __uint_as_float(uv.y & 0xffff0000u);
#pragma unroll
        for (int h = 0; h < 8; ++h) {
            float ww = wb[h * 1024 + k];
            acc[h].x = fmaf(ww, x0, acc[h].x);
            acc[h].y = fmaf(ww, x1, acc[h].y);
            acc[h].z = fmaf(ww, x2, acc[h].z);
            acc[h].w = fmaf(ww, x3, acc[h].w);
        }
    }
#pragma unroll
    for (int h = 0; h < 8; ++h) {
        float* dst = u + ((size_t)(b * 8 + h)) * 1024 + c4 * 4;
        atomicAdd(dst + 0, acc[h].x);
        atomicAdd(dst + 1, acc[h].y);
        atomicAdd(dst + 2, acc[h].z);
        atomicAdd(dst + 3, acc[h].w);
    }
}

// ---------- small GEMM with split-K ----------
__global__ __launch_bounds__(256) void sgemm_kernel(
    const float* __restrict__ A, int lda, long sAz,
    const float* __restrict__ Bm, int ldb, long sBz,
    const float* __restrict__ bias, long sBiasz,
    float* __restrict__ C, int ldc, long sCz,
    int M, int N, int K, float alpha, int nks)
{
    const int z = blockIdx.z;
    const int ks = blockIdx.x % nks;
    const int mt = blockIdx.x / nks;
    const int Kc = K / nks;
    A += (size_t)z * sAz;
    Bm += (size_t)z * sBz;
    C += (size_t)z * sCz;
    const float* bptr = bias ? bias + (size_t)z * sBiasz : nullptr;
    __shared__ float As[64 * 36];
    __shared__ float Bs[32 * 68];
    const int tid = threadIdx.x;
    const int row0 = mt * 64, col0 = blockIdx.y * 64;
    const int ty = tid >> 4, tx = tid & 15;
    float acc[4][4] = {};
    const int aflat = tid * 8;
    const int ar = aflat >> 5, ac = aflat & 31;
    const int br = aflat >> 6, bc = aflat & 63;
    for (int k0 = ks * Kc; k0 < (ks + 1) * Kc; k0 += 32) {
        __syncthreads();
        float4 va0 = make_float4(0.f, 0.f, 0.f, 0.f), va1 = va0;
        if (row0 + ar < M) {
            const float* src = A + (size_t)(row0 + ar) * lda + k0 + ac;
            va0 = *(const float4*)src;
            va1 = *(const float4*)(src + 4);
        }
        *(float4*)&As[ar * 36 + ac] = va0;
        *(float4*)&As[ar * 36 + ac + 4] = va1;
        {
            const float* srcb = Bm + (size_t)(k0 + br) * ldb + col0 + bc;
            *(float4*)&Bs[br * 68 + bc] = *(const float4*)srcb;
            *(float4*)&Bs[br * 68 + bc + 4] = *(const float4*)(srcb + 4);
        }
        __syncthreads();
#pragma unroll
        for (int kk = 0; kk < 32; ++kk) {
            float a0 = As[(ty * 4 + 0) * 36 + kk];
            float a1 = As[(ty * 4 + 1) * 36 + kk];
            float a2 = As[(ty * 4 + 2) * 36 + kk];
            float a3 = As[(ty * 4 + 3) * 36 + kk];
            float b0 = Bs[kk * 68 + tx * 4 + 0];
            float b1 = Bs[kk * 68 + tx * 4 + 1];
            float b2 = Bs[kk * 68 + tx * 4 + 2];
            float b3 = Bs[kk * 68 + tx * 4 + 3];
            acc[0][0] = fmaf(a0, b0, acc[0][0]); acc[0][1] = fmaf(a0, b1, acc[0][1]);
            acc[0][2] = fmaf(a0, b2, acc[0][2]); acc[0][3] = fmaf(a0, b3, acc[0][3]);
            acc[1][0] = fmaf(a1, b0, acc[1][0]); acc[1][1] = fmaf(a1, b1, acc[1][1]);
            acc[1][2] = fmaf(a1, b2, acc[1][2]); acc[1][3] = fmaf(a1, b3, acc[1][3]);
            acc[2][0] = fmaf(a2, b0, acc[2][0]); acc[2][1] = fmaf(a2, b1, acc[2][1]);
            acc[2][2] = fmaf(a2, b2, acc[2][2]); acc[2][3] = fmaf(a2, b3, acc[2][3]);
            acc[3][0] = fmaf(a3, b0, acc[3][0]); acc[3][1] = fmaf(a3, b1, acc[3][1]);
            acc[3][2] = fmaf(a3, b2, acc[3][2]); acc[3][3] = fmaf(a3, b3, acc[3][3]);
        }
    }
#pragma unroll
    for (int i = 0; i < 4; ++i) {
        int r = row0 + ty * 4 + i;
        if (r >= M) continue;
#pragma unroll
        for (int j = 0; j < 4; ++j) {
            int c = col0 + tx * 4 + j;
            float v = alpha * acc[i][j] + ((bptr && ks == 0) ? bptr[c] : 0.f);
            if (nks > 1) atomicAdd(&C[(size_t)r * ldc + c], v);
            else C[(size_t)r * ldc + c] = v;
        }
    }
}

// ---------- fused Ge/Ee: z=0 -> Ge = gbuf @ rg_w1[:1024], z=1 -> Ee = emb @ rg_w1[1024:] ----------
__global__ __launch_bounds__(256) void sgemm_ge_ee_kernel(
    const float* __restrict__ gbuf, const float* __restrict__ emb,
    const float* __restrict__ rg_w1, float* __restrict__ Ge, float* __restrict__ Ee)
{
    const int z = blockIdx.z;
    const float* A = z ? emb : gbuf;
    const float* Bm = rg_w1 + (size_t)z * 1048576;
    float* C = z ? Ee : Ge;
    const int M = z ? 64 : 16;
    const int nks = 8, Kc = 128;
    const int ks = blockIdx.x % nks;
    __shared__ float As[64 * 36];
    __shared__ float Bs[32 * 68];
    const int tid = threadIdx.x;
    const int col0 = blockIdx.y * 64;
    const int ty = tid >> 4, tx = tid & 15;
    float acc[4][4] = {};
    const int aflat = tid * 8;
    const int ar = aflat >> 5, ac = aflat & 31;
    const int br = aflat >> 6, bc = aflat & 63;
    for (int k0 = ks * Kc; k0 < (ks + 1) * Kc; k0 += 32) {
        __syncthreads();
        float4 va0 = make_float4(0.f, 0.f, 0.f, 0.f), va1 = va0;
        if (ar < M) {
            const float* src = A + (size_t)ar * 1024 + k0 + ac;
            va0 = *(const float4*)src;
            va1 = *(const float4*)(src + 4);
        }
        *(float4*)&As[ar * 36 + ac] = va0;
        *(float4*)&As[ar * 36 + ac + 4] = va1;
        {
            const float* srcb = Bm + (size_t)(k0 + br) * 1024 + col0 + bc;
            *(float4*)&Bs[br * 68 + bc] = *(const float4*)srcb;
            *(float4*)&Bs[br * 68 + bc + 4] = *(const float4*)(srcb + 4);
        }
        __syncthreads();
#pragma unroll
        for (int kk = 0; kk < 32; ++kk) {
            float a0 = As[(ty * 4 + 0) * 36 + kk];
            float a1 = As[(ty * 4 + 1) * 36 + kk];
            float a2 = As[(ty * 4 + 2) * 36 + kk];
            float a3 = As[(ty * 4 + 3) * 36 + kk];
            float b0 = Bs[kk * 68 + tx * 4 + 0];
            float b1 = Bs[kk * 68 + tx * 4 + 1];
            float b2 = Bs[kk * 68 + tx * 4 + 2];
            float b3 = Bs[kk * 68 + tx * 4 + 3];
            acc[0][0] = fmaf(a0, b0, acc[0][0]); acc[0][1] = fmaf(a0, b1, acc[0][1]);
            acc[0][2] = fmaf(a0, b2, acc[0][2]); acc[0][3] = fmaf(a0, b3, acc[0][3]);
            acc[1][0] = fmaf(a1, b0, acc[1][0]); acc[1][1] = fmaf(a1, b1, acc[1][1]);
            acc[1][2] = fmaf(a1, b2, acc[1][2]); acc[1][3] = fmaf(a1, b3, acc[1][3]);
            acc[2][0] = fmaf(a2, b0, acc[2][0]); acc[2][1] = fmaf(a2, b1, acc[2][1]);
            acc[2][2] = fmaf(a2, b2, acc[2][2]); acc[2][3] = fmaf(a2, b3, acc[2][3]);
            acc[3][0] = fmaf(a3, b0, acc[3][0]); acc[3][1] = fmaf(a3, b1, acc[3][1]);
            acc[3][2] = fmaf(a3, b2, acc[3][2]); acc[3][3] = fmaf(a3, b3, acc[3][3]);
        }
    }
#pragma unroll
    for (int i = 0; i < 4; ++i) {
        int r = ty * 4 + i;
        if (r >= M) continue;
#pragma unroll
        for (int j = 0; j < 4; ++j) {
            int c = col0 + tx * 4 + j;
            atomicAdd(&C[(size_t)r * 1024 + c], acc[i][j]);
        }
    }
}

// ---------- fused gate: h1=tanh -> logits -> softmax -> DR = rw @ emb ----------
__global__ __launch_bounds__(256) void gate_kernel(
    const float* __restrict__ Ge, const float* __restrict__ Ee, const float* __restrict__ rg_b1,
    const float* __restrict__ rg_w2, const float* __restrict__ rg_b2,
    const float* __restrict__ emb, float* __restrict__ DR)
{
    const int row = blockIdx.x;       // 1024 = b*64+n
    const int b = row >> 6, n = row & 63;
    __shared__ float h[1024];
    __shared__ float red[256];
    __shared__ float rw[64];
    const int tid = threadIdx.x;
    for (int c = tid; c < 1024; c += 256)
        h[c] = tanhf(Ge[b * 1024 + c] + Ee[n * 1024 + c] + rg_b1[c]);
    __syncthreads();
    const int j = tid & 63, ch = tid >> 6;
    float part = 0.f;
    const float* w2p = rg_w2 + (size_t)(ch * 256) * 64 + j;
    for (int c = 0; c < 256; ++c)
        part = fmaf(h[ch * 256 + c], w2p[c * 64], part);
    red[tid] = part;
    __syncthreads();
    if (tid < 64) {
        float lg = red[tid] + red[tid + 64] + red[tid + 128] + red[tid + 192] + rg_b2[j];
        float m = lg;
#pragma unroll
        for (int off = 1; off < 64; off <<= 1) m = fmaxf(m, __shfl_xor(m, off, 64));
        float e = __expf(lg - m);
        float s = e;
#pragma unroll
        for (int off = 1; off < 64; off <<= 1) s += __shfl_xor(s, off, 64);
        rw[tid] = e / s;
    }
    __syncthreads();
    float4 acc = make_float4(0.f, 0.f, 0.f, 0.f);
    const float4* E4 = (const float4*)emb;
    for (int nn = 0; nn < 64; ++nn) {
        float wv = rw[nn];
        float4 ev = E4[nn * 256 + tid];
        acc.x = fmaf(wv, ev.x, acc.x);
        acc.y = fmaf(wv, ev.y, acc.y);
        acc.z = fmaf(wv, ev.z, acc.z);
        acc.w = fmaf(wv, ev.w, acc.w);
    }
    *(float4*)&DR[(size_t)row * 1024 + tid * 4] = acc;
}

// ---------- heads part 1: split-K partial GEMM ----------
__global__ __launch_bounds__(256) void heads_p1_kernel(
    const float* __restrict__ g, const float* __restrict__ DR,
    const float* __restrict__ rw1, const float* __restrict__ cw1,
    float* __restrict__ hpart)
{
    const int n = blockIdx.x, task = blockIdx.y, ksl = blockIdx.z;
    __shared__ float combs[16 * 128];
    const int tid = threadIdx.x;
    for (int i = tid; i < 2048; i += 256) {
        int b = i >> 7, c = i & 127;
        int gc = ksl * 128 + c;
        combs[i] = g[b * 1024 + gc] + DR[((size_t)(b * 64 + n)) * 1024 + gc];
    }
    __syncthreads();
    const int j = tid & 127, sub = tid >> 7;
    const float* W1 = (task ? cw1 : rw1) + (size_t)n * 131072 + (size_t)ksl * 128 * 128;
    float a[8] = {};
    for (int c4 = 0; c4 < 32; ++c4) {
        const float w0 = W1[(c4 * 4 + 0) * 128 + j];
        const float w1 = W1[(c4 * 4 + 1) * 128 + j];
        const float w2 = W1[(c4 * 4 + 2) * 128 + j];
        const float w3 = W1[(c4 * 4 + 3) * 128 + j];
#pragma unroll
        for (int bb = 0; bb < 8; ++bb) {
            float4 cv = *(const float4*)&combs[(sub * 8 + bb) * 128 + c4 * 4];
            a[bb] = fmaf(cv.x, w0, a[bb]);
            a[bb] = fmaf(cv.y, w1, a[bb]);
            a[bb] = fmaf(cv.z, w2, a[bb]);
            a[bb] = fmaf(cv.w, w3, a[bb]);
        }
    }
    float* dst = hpart + (((size_t)(ksl * 2 + task) * 64 + n) * 16 + sub * 8) * 128 + j;
#pragma unroll
    for (int bb = 0; bb < 8; ++bb) dst[bb * 128] = a[bb];
}

// ---------- heads part 2 ----------
__global__ __launch_bounds__(256) void heads_p2_kernel(
    const float* __restrict__ hpart,
    const float* __restrict__ rb1, const float* __restrict__ rw2, const float* __restrict__ rb2,
    const float* __restrict__ cb1, const float* __restrict__ cw2, const float* __restrict__ cb2,
    float* __restrict__ out)
{
    const int n = blockIdx.x, task = blockIdx.y;
    const int tid = threadIdx.x;
    const int b = tid >> 4, jg = tid & 15;
    const float* b1 = (task ? cb1 : rb1) + n * 128 + jg * 8;
    const float* W2 = (task ? cw2 : rw2) + n * 128 + jg * 8;
    float s = 0.f;
#pragma unroll
    for (int k = 0; k < 8; ++k) {
        float h = b1[k];
#pragma unroll
        for (int ksl = 0; ksl < 8; ++ksl)
            h += hpart[(((size_t)(ksl * 2 + task) * 64 + n) * 16 + b) * 128 + jg * 8 + k];
        s = fmaf(fmaxf(h, 0.f), W2[k], s);
    }
#pragma unroll
    for (int off = 1; off < 16; off <<= 1) s += __shfl_xor(s, off, 16);
    if (jg == 0) {
        s += (task ? cb2 : rb2)[n];
        float r = task ? (1.f / (1.f + __expf(-s)))
                       : (fmaxf(s, 0.f) + log1pf(__expf(-fabsf(s))));
        out[task * 1024 + b * 64 + n] = r;
    }
}

// ---------- launch ----------
extern "C" void kernel_launch(void* const* d_in, const int* in_sizes, int n_in,
                              void* d_out, int out_size, void* d_ws, size_t ws_size,
                              hipStream_t stream)
{
    const float* x      = (const float*)d_in[0];
    const float* wq     = (const float*)d_in[1];
    const float* bq     = (const float*)d_in[2];
    const float* wk     = (const float*)d_in[3];
    const float* bk     = (const float*)d_in[4];
    const float* wv     = (const float*)d_in[5];
    const float* bv     = (const float*)d_in[6];
    const float* wo     = (const float*)d_in[7];
    const float* bo     = (const float*)d_in[8];
    const float* emb    = (const float*)d_in[9];
    const float* rg_w1  = (const float*)d_in[10];
    const float* rg_b1  = (const float*)d_in[11];
    const float* rg_w2  = (const float*)d_in[12];
    const float* rg_b2  = (const float*)d_in[13];
    const float* reg_w1 = (const float*)d_in[14];
    const float* reg_b1 = (const float*)d_in[15];
    const float* reg_w2 = (const float*)d_in[16];
    const float* reg_b2 = (const float*)d_in[17];
    const float* cls_w1 = (const float*)d_in[18];
    const float* cls_b1 = (const float*)d_in[19];
    const float* cls_w2 = (const float*)d_in[20];
    const float* cls_b2 = (const float*)d_in[21];

    char* ws = (char*)d_ws;
    size_t off = 0;
    auto alloc = [&](size_t bytes) { size_t cur = off; off += (bytes + 255) & ~(size_t)255; return cur; };

    ushort_t* xb  = (ushort_t*)(ws + alloc((size_t)16777216 * 2));
    ushort_t* wqT = (ushort_t*)(ws + alloc((size_t)1048576 * 2));
    ushort_t* wkT = (ushort_t*)(ws + alloc((size_t)1048576 * 2));
    ushort_t* Qb  = (ushort_t*)(ws + alloc((size_t)16777216 * 2));
    ushort_t* Kb  = (ushort_t*)(ws + alloc((size_t)16777216 * 2));
    size_t zero_beg = off;
    float* wcol = (float*)(ws + alloc((size_t)131072 * 4));
    float* u    = (float*)(ws + alloc((size_t)131072 * 4));
    float* cm   = (float*)(ws + alloc((size_t)16384 * 4));
    float* gbuf = (float*)(ws + alloc((size_t)16384 * 4));
    float* Ge   = (float*)(ws + alloc((size_t)16384 * 4));
    float* Ee   = (float*)(ws + alloc((size_t)65536 * 4));
    size_t zero_end = off;
    float* DR    = (float*)(ws + alloc((size_t)1048576 * 4));
    float* hpart = (float*)(ws + alloc((size_t)2097152 * 4));

    hipMemsetAsync(ws + zero_beg, 0, zero_end - zero_beg, stream);

    prep_tr_kernel<<<8704, 256, 0, stream>>>(x, xb, wq, wk, wqT, wkT);
    gemm_qk_kernel<<<dim3(128, 8), 512, 0, stream>>>(xb, wqT, wkT, bq, bk, Qb, Kb);
    attn_mfma_kernel<<<dim3(128, 4), 512, 0, stream>>>(Qb, Kb, wcol);
    u_kernel<<<dim3(16, 16), 256, 0, stream>>>(xb, wcol, u);
    sgemm_kernel<<<dim3(4, 2, 8), 256, 0, stream>>>(u, 8192, 1024, wv, 1024, 128, bv, 128,
                                                    cm, 1024, 128, 16, 128, 1024, 1.f / 1024.f, 4);
    sgemm_kernel<<<dim3(8, 16, 1), 256, 0, stream>>>(cm, 1024, 0, wo, 1024, 0, bo, 0,
                                                     gbuf, 1024, 0, 16, 1024, 1024, 1.f, 8);
    sgemm_ge_ee_kernel<<<dim3(8, 16, 2), 256, 0, stream>>>(gbuf, emb, rg_w1, Ge, Ee);
    gate_kernel<<<1024, 256, 0, stream>>>(Ge, Ee, rg_b1, rg_w2, rg_b2, emb, DR);
    heads_p1_kernel<<<dim3(64, 2, 8), 256, 0, stream>>>(gbuf, DR, reg_w1, cls_w1, hpart);
    heads_p2_kernel<<<dim3(64, 2), 256, 0, stream>>>(hpart, reg_b1, reg_w2, reg_b2,
                                                     cls_b1, cls_w2, cls_b2, (float*)d_out);
    (void)in_sizes; (void)n_in; (void)out_size; (void)ws_size;
}

// Round 5
// 452.797 us; speedup vs baseline: 1.1465x; 1.1465x over previous
//
#include <hip/hip_runtime.h>

typedef unsigned short ushort_t;
typedef __attribute__((ext_vector_type(8))) short short8;
typedef __attribute__((ext_vector_type(4))) float floatx4;

// ---------- helpers ----------
__device__ __forceinline__ ushort_t f2bf(float f) {
    unsigned u = __float_as_uint(f);
    return (ushort_t)((u + 0x7fffu + ((u >> 16) & 1u)) >> 16);
}
__device__ __forceinline__ void gll16(const void* g, void* l) {
    __builtin_amdgcn_global_load_lds(
        (const __attribute__((address_space(1))) unsigned int*)g,
        (__attribute__((address_space(3))) unsigned int*)l, 16, 0, 0);
}
#if __has_builtin(__builtin_amdgcn_exp2f)
#define EXP2f(x) __builtin_amdgcn_exp2f(x)
#else
#define EXP2f(x) exp2f(x)
#endif

// ---------- fused: cast x -> bf16  +  LDS-tiled transpose+cast of wq/wk ----------
__global__ __launch_bounds__(256) void prep_tr_kernel(
    const float* __restrict__ x, ushort_t* __restrict__ xb,
    const float* __restrict__ wq, const float* __restrict__ wk,
    ushort_t* __restrict__ wqT, ushort_t* __restrict__ wkT)
{
    __shared__ float t[64][65];
    const int bid = blockIdx.x;
    const int tid = threadIdx.x;
    if (bid < 8192) {
        size_t i = ((size_t)bid * 256 + tid) * 8;
        float4 v0 = *(const float4*)(x + i);
        float4 v1 = *(const float4*)(x + i + 4);
        uint4 o;
        o.x = (unsigned)f2bf(v0.x) | ((unsigned)f2bf(v0.y) << 16);
        o.y = (unsigned)f2bf(v0.z) | ((unsigned)f2bf(v0.w) << 16);
        o.z = (unsigned)f2bf(v1.x) | ((unsigned)f2bf(v1.y) << 16);
        o.w = (unsigned)f2bf(v1.z) | ((unsigned)f2bf(v1.w) << 16);
        *(uint4*)(xb + i) = o;
        return;
    }
    const int b2 = bid - 8192;               // 0..511
    const int bx = b2 & 15, by = (b2 >> 4) & 15, bz = b2 >> 8;
    const float* src = bz ? wk : wq;
    ushort_t* dst = bz ? wkT : wqT;
    const int k0 = bx * 64, n0 = by * 64;
    const int rr = tid >> 4, cc = (tid & 15) * 4;
#pragma unroll
    for (int p = 0; p < 4; ++p) {
        float4 v = *(const float4*)(src + (size_t)(k0 + p * 16 + rr) * 1024 + n0 + cc);
        t[p * 16 + rr][cc + 0] = v.x;
        t[p * 16 + rr][cc + 1] = v.y;
        t[p * 16 + rr][cc + 2] = v.z;
        t[p * 16 + rr][cc + 3] = v.w;
    }
    __syncthreads();
#pragma unroll
    for (int p = 0; p < 4; ++p) {
        int nl = p * 16 + rr;
        uint2 o;
        o.x = (unsigned)f2bf(t[cc + 0][nl]) | ((unsigned)f2bf(t[cc + 1][nl]) << 16);
        o.y = (unsigned)f2bf(t[cc + 2][nl]) | ((unsigned)f2bf(t[cc + 3][nl]) << 16);
        *(uint2*)(dst + (size_t)(n0 + nl) * 1024 + k0 + cc) = o;
    }
}

// ---------- MFMA bf16 GEMM: Q and K fused per block, shared A-tile ----------
// R3-verified 2-phase structure (93 us). R4's 4-deep counted-vmcnt pipeline
// REGRESSED (120 us: 96KB LDS -> 1 blk/CU, FETCH 50->82MB) - do not re-add.
__global__ __launch_bounds__(512, 4) void gemm_qk_kernel(
    const ushort_t* __restrict__ xb, const ushort_t* __restrict__ wqT, const ushort_t* __restrict__ wkT,
    const float* __restrict__ bq, const float* __restrict__ bk,
    ushort_t* __restrict__ Qb, ushort_t* __restrict__ Kb)
{
    const int bm = blockIdx.x;          // 128 M-tiles of 128
    const int bn = blockIdx.y;          // 8 N-tiles of 128

    __shared__ ushort_t a_lds[2][128 * 32];    // 2 x 8 KB
    __shared__ ushort_t q_lds[2][128 * 32];
    __shared__ ushort_t k_lds[2][128 * 32];

    const int tid = threadIdx.x;
    const int lane = tid & 63;
    const int wave = tid >> 6;          // 0..7
    const int wmat = wave >> 2;         // 0=Q, 1=K
    const int wr = (wave >> 1) & 1, wc = wave & 1;
    const int l16 = lane & 15, quad = lane >> 4;
    const int qs = quad ^ ((l16 >> 1) & 3);   // swizzled chunk for fragment reads

    floatx4 acc[4][4];
    const floatx4 zero4 = {0.f, 0.f, 0.f, 0.f};
#pragma unroll
    for (int i = 0; i < 4; ++i)
#pragma unroll
        for (int j = 0; j < 4; ++j) acc[i][j] = zero4;

    // staging: thread t covers row t>>2, 16B-chunk t&3 of a 128x32 tile;
    // source chunk pre-swizzled with (row>>1)&3 == (t>>3)&3 (involution).
    const int srow = tid >> 2;
    const int skof = ((tid & 3) ^ ((tid >> 3) & 3)) * 8;
    const ushort_t* gA = xb + (size_t)(bm * 128 + srow) * 1024 + skof;
    const ushort_t* gQ = wqT + (size_t)(bn * 128 + srow) * 1024 + skof;
    const ushort_t* gK = wkT + (size_t)(bn * 128 + srow) * 1024 + skof;

    auto issue = [&](int buf, int k0) {
        gll16(gA + k0, &a_lds[buf][wave * 512]);
        gll16(gQ + k0, &q_lds[buf][wave * 512]);
        gll16(gK + k0, &k_lds[buf][wave * 512]);
    };

    const ushort_t* lbase = wmat ? k_lds[0] : q_lds[0];
    const int lstride = wmat ? (int)(k_lds[1] - k_lds[0]) : (int)(q_lds[1] - q_lds[0]);

    auto compute = [&](int buf) {
        const ushort_t* la = a_lds[buf];
        const ushort_t* lb = lbase + buf * lstride;
        short8 afr[4], bfr[4];
#pragma unroll
        for (int mi = 0; mi < 4; ++mi)
            afr[mi] = *(const short8*)&la[(wr * 64 + mi * 16 + l16) * 32 + qs * 8];
#pragma unroll
        for (int ni = 0; ni < 4; ++ni)
            bfr[ni] = *(const short8*)&lb[(wc * 64 + ni * 16 + l16) * 32 + qs * 8];
#pragma unroll
        for (int mi = 0; mi < 4; ++mi)
#pragma unroll
            for (int ni = 0; ni < 4; ++ni)
                acc[mi][ni] = __builtin_amdgcn_mfma_f32_16x16x32_bf16(afr[mi], bfr[ni], acc[mi][ni], 0, 0, 0);
    };

    issue(0, 0);
#pragma unroll 4
    for (int kt = 0; kt < 31; ++kt) {
        __syncthreads();
        issue((kt + 1) & 1, (kt + 1) * 32);
        compute(kt & 1);
    }
    __syncthreads();
    compute(1);

    // epilogue (per-wave matrix select; single base + immediate offsets)
    ushort_t* Out = wmat ? Kb : Qb;
    const float* bias = wmat ? bk : bq;
    // Q postscale = log2(e)/sqrt(128): attention uses exp2 directly.
    const float postscale = wmat ? 1.0f : 0.12751744900508692f;

    const int bq_ = bm >> 3;                               // batch index (constant)
    const int sb = (bm & 7) * 128 + wr * 64 + quad * 4;    // seq base (+ mi*16 + r)
    const int dc = wc * 64 + l16;                          // head-dim base (+ ni*16)
    float bp[4];
#pragma unroll
    for (int ni = 0; ni < 4; ++ni) bp[ni] = bias[bn * 128 + dc + ni * 16] * postscale;
    ushort_t* ob = Out + ((size_t)(bq_ * 8 + bn) * 1024 + sb) * 128 + dc;
#pragma unroll
    for (int mi = 0; mi < 4; ++mi)
#pragma unroll
        for (int ni = 0; ni < 4; ++ni) {
            ushort_t* p = ob + mi * 2048 + ni * 16;
#pragma unroll
            for (int r = 0; r < 4; ++r)
                p[r * 128] = f2bf(fmaf(acc[mi][ni][r], postscale, bp[ni]));
        }
}

// ---------- attention column sums via MFMA, QBLK=256, 8 waves share K-tile ----------
__global__ __launch_bounds__(512, 4) void attn_mfma_kernel(
    const ushort_t* __restrict__ Qb,   // [bh][1024][128] bf16 (exp2-scaled)
    const ushort_t* __restrict__ Kb,   // [bh][1024][128] bf16
    float* __restrict__ wout)          // [bh][1024], zero-init
{
    const int bh = blockIdx.x;         // 128
    const int qt = blockIdx.y;         // 4 q-tiles of 256 rows
    __shared__ ushort_t ks[2][64 * 128]; // 2 x 16 KB, XOR-swizzled 16B granules

    const int tid = threadIdx.x;
    const int wave = tid >> 6, lane = tid & 63;
    const int l16 = lane & 15, quad = lane >> 4;

    const ushort_t* Ksrc = Kb + (size_t)bh * 1024 * 128;

    int srcoff[2];
#pragma unroll
    for (int c = 0; c < 2; ++c) {
        int r = c * 32 + (tid >> 4);
        int g = (tid & 15) ^ (r & 15);
        srcoff[c] = r * 128 + g * 8;
    }

    auto issue = [&](int buf, int kt) {
        const ushort_t* src = Ksrc + (size_t)kt * 8192;
#pragma unroll
        for (int c = 0; c < 2; ++c)
            gll16(src + srcoff[c], &ks[buf][c * 4096 + wave * 512]);
    };

    // Q fragments, kept in registers for both passes (wave owns 32 Q-rows)
    short8 aq[2][4];
    {
        const ushort_t* qsrc = Qb + ((size_t)bh * 1024 + qt * 256 + wave * 32) * 128;
#pragma unroll
        for (int mi = 0; mi < 2; ++mi)
#pragma unroll
            for (int ksp = 0; ksp < 4; ++ksp)
                aq[mi][ksp] = *(const short8*)(qsrc + (size_t)(mi * 16 + l16) * 128 + ksp * 32 + quad * 8);
    }

    const floatx4 zero4 = {0.f, 0.f, 0.f, 0.f};
    float lsum[2][4];
#pragma unroll
    for (int mi = 0; mi < 2; ++mi)
#pragma unroll
        for (int r = 0; r < 4; ++r) lsum[mi][r] = 0.f;

    issue(0, 0);

    // ---- pass 1: row sums of exp2(s) ----
    for (int kt = 0; kt < 16; ++kt) {
        __syncthreads();
        if (kt < 15) issue((kt + 1) & 1, kt + 1);
        const ushort_t* kbuf = ks[kt & 1];
        floatx4 acc[2][4];
#pragma unroll
        for (int mi = 0; mi < 2; ++mi)
#pragma unroll
            for (int ni = 0; ni < 4; ++ni) acc[mi][ni] = zero4;
#pragma unroll
        for (int ksp = 0; ksp < 4; ++ksp) {
            short8 bk[4];
#pragma unroll
            for (int ni = 0; ni < 4; ++ni) {
                int n = ni * 16 + l16;
                int gs = (ksp * 4 + quad) ^ (n & 15);
                bk[ni] = *(const short8*)&kbuf[n * 128 + gs * 8];
            }
#pragma unroll
            for (int mi = 0; mi < 2; ++mi)
#pragma unroll
                for (int ni = 0; ni < 4; ++ni)
                    acc[mi][ni] = __builtin_amdgcn_mfma_f32_16x16x32_bf16(aq[mi][ksp], bk[ni], acc[mi][ni], 0, 0, 0);
        }
#pragma unroll
        for (int mi = 0; mi < 2; ++mi)
#pragma unroll
            for (int r = 0; r < 4; ++r) {
                float s = 0.f;
#pragma unroll
                for (int ni = 0; ni < 4; ++ni) s += EXP2f(acc[mi][ni][r]);
                lsum[mi][r] += s;
            }
    }

    issue(0, 0);    // prefetch pass-2 tile 0

    float invl[2][4];
#pragma unroll
    for (int mi = 0; mi < 2; ++mi)
#pragma unroll
        for (int r = 0; r < 4; ++r) {
            float s = lsum[mi][r];
#pragma unroll
            for (int off = 1; off < 16; off <<= 1) s += __shfl_xor(s, off, 16);
            invl[mi][r] = 1.f / s;
        }

    // ---- pass 2: column sums of exp2(s)/l ----
    for (int kt = 0; kt < 16; ++kt) {
        __syncthreads();
        if (kt < 15) issue((kt + 1) & 1, kt + 1);
        const ushort_t* kbuf = ks[kt & 1];
        floatx4 acc[2][4];
#pragma unroll
        for (int mi = 0; mi < 2; ++mi)
#pragma unroll
            for (int ni = 0; ni < 4; ++ni) acc[mi][ni] = zero4;
#pragma unroll
        for (int ksp = 0; ksp < 4; ++ksp) {
            short8 bk[4];
#pragma unroll
            for (int ni = 0; ni < 4; ++ni) {
                int n = ni * 16 + l16;
                int gs = (ksp * 4 + quad) ^ (n & 15);
                bk[ni] = *(const short8*)&kbuf[n * 128 + gs * 8];
            }
#pragma unroll
            for (int mi = 0; mi < 2; ++mi)
#pragma unroll
                for (int ni = 0; ni < 4; ++ni)
                    acc[mi][ni] = __builtin_amdgcn_mfma_f32_16x16x32_bf16(aq[mi][ksp], bk[ni], acc[mi][ni], 0, 0, 0);
        }
#pragma unroll
        for (int ni = 0; ni < 4; ++ni) {
            float s = 0.f;
#pragma unroll
            for (int mi = 0; mi < 2; ++mi)
#pragma unroll
                for (int r = 0; r < 4; ++r)
                    s += EXP2f(acc[mi][ni][r]) * invl[mi][r];
            s += __shfl_xor(s, 16, 64);
            s += __shfl_xor(s, 32, 64);
            if (quad == 0) atomicAdd(&wout[bh * 1024 + kt * 64 + ni * 16 + l16], s);
        }
    }
}

// ---------- u[b,h,:] = sum_k w[b,h,k] * xb[b,k,:]  — no atomics ----------
// grid (16 b, 16 d-chunks of 64); in-block k-split over 16 k-parts,
// LDS float4 reduce, direct coalesced store. Replaces 2M-atomic split-K.
__global__ __launch_bounds__(256) void u_kernel(const ushort_t* __restrict__ xb,
                                                const float* __restrict__ w,
                                                float* __restrict__ u)
{
    const int b = blockIdx.x, dc = blockIdx.y;
    const int tid = threadIdx.x;
    const int kp = tid >> 4, dli = tid & 15;
    const int d0 = dc * 64;
    __shared__ float4 accl[16][8][16];     // 32 KB

    float4 acc[8];
#pragma unroll
    for (int h = 0; h < 8; ++h) acc[h] = make_float4(0.f, 0.f, 0.f, 0.f);

    const ushort_t* Xp = xb + ((size_t)(b * 1024 + kp * 64)) * 1024 + d0 + dli * 4;
    const float* wb = w + b * 8192 + kp * 64;
    for (int k = 0; k < 64; ++k) {
        uint2 uv = *(const uint2*)(Xp + (size_t)k * 1024);
        float x0 = __uint_as_float(uv.x << 16);
        float x1 = __uint_as_float(uv.x & 0xffff0000u);
        float x2 = __uint_as_float(uv.y << 16);
        float x3 = __uint_as_float(uv.y & 0xffff0000u);
#pragma unroll
        for (int h = 0; h < 8; ++h) {
            float ww = wb[h * 1024 + k];
            acc[h].x = fmaf(ww, x0, acc[h].x);
            acc[h].y = fmaf(ww, x1, acc[h].y);
            acc[h].z = fmaf(ww, x2, acc[h].z);
            acc[h].w = fmaf(ww, x3, acc[h].w);
        }
    }
#pragma unroll
    for (int h = 0; h < 8; ++h) accl[kp][h][dli] = acc[h];
    __syncthreads();
    if (tid < 128) {
        const int h = tid >> 4, di = tid & 15;
        float4 s = accl[0][h][di];
#pragma unroll
        for (int k2 = 1; k2 < 16; ++k2) {
            float4 v = accl[k2][h][di];
            s.x += v.x; s.y += v.y; s.z += v.z; s.w += v.w;
        }
        *(float4*)&u[((size_t)(b * 8 + h)) * 1024 + d0 + di * 4] = s;
    }
}

// ---------- small GEMM with split-K ----------
__global__ __launch_bounds__(256) void sgemm_kernel(
    const float* __restrict__ A, int lda, long sAz,
    const float* __restrict__ Bm, int ldb, long sBz,
    const float* __restrict__ bias, long sBiasz,
    float* __restrict__ C, int ldc, long sCz,
    int M, int N, int K, float alpha, int nks)
{
    const int z = blockIdx.z;
    const int ks = blockIdx.x % nks;
    const int mt = blockIdx.x / nks;
    const int Kc = K / nks;
    A += (size_t)z * sAz;
    Bm += (size_t)z * sBz;
    C += (size_t)z * sCz;
    const float* bptr = bias ? bias + (size_t)z * sBiasz : nullptr;
    __shared__ float As[64 * 36];
    __shared__ float Bs[32 * 68];
    const int tid = threadIdx.x;
    const int row0 = mt * 64, col0 = blockIdx.y * 64;
    const int ty = tid >> 4, tx = tid & 15;
    float acc[4][4] = {};
    const int aflat = tid * 8;
    const int ar = aflat >> 5, ac = aflat & 31;
    const int br = aflat >> 6, bc = aflat & 63;
    for (int k0 = ks * Kc; k0 < (ks + 1) * Kc; k0 += 32) {
        __syncthreads();
        float4 va0 = make_float4(0.f, 0.f, 0.f, 0.f), va1 = va0;
        if (row0 + ar < M) {
            const float* src = A + (size_t)(row0 + ar) * lda + k0 + ac;
            va0 = *(const float4*)src;
            va1 = *(const float4*)(src + 4);
        }
        *(float4*)&As[ar * 36 + ac] = va0;
        *(float4*)&As[ar * 36 + ac + 4] = va1;
        {
            const float* srcb = Bm + (size_t)(k0 + br) * ldb + col0 + bc;
            *(float4*)&Bs[br * 68 + bc] = *(const float4*)srcb;
            *(float4*)&Bs[br * 68 + bc + 4] = *(const float4*)(srcb + 4);
        }
        __syncthreads();
#pragma unroll
        for (int kk = 0; kk < 32; ++kk) {
            float a0 = As[(ty * 4 + 0) * 36 + kk];
            float a1 = As[(ty * 4 + 1) * 36 + kk];
            float a2 = As[(ty * 4 + 2) * 36 + kk];
            float a3 = As[(ty * 4 + 3) * 36 + kk];
            float b0 = Bs[kk * 68 + tx * 4 + 0];
            float b1 = Bs[kk * 68 + tx * 4 + 1];
            float b2 = Bs[kk * 68 + tx * 4 + 2];
            float b3 = Bs[kk * 68 + tx * 4 + 3];
            acc[0][0] = fmaf(a0, b0, acc[0][0]); acc[0][1] = fmaf(a0, b1, acc[0][1]);
            acc[0][2] = fmaf(a0, b2, acc[0][2]); acc[0][3] = fmaf(a0, b3, acc[0][3]);
            acc[1][0] = fmaf(a1, b0, acc[1][0]); acc[1][1] = fmaf(a1, b1, acc[1][1]);
            acc[1][2] = fmaf(a1, b2, acc[1][2]); acc[1][3] = fmaf(a1, b3, acc[1][3]);
            acc[2][0] = fmaf(a2, b0, acc[2][0]); acc[2][1] = fmaf(a2, b1, acc[2][1]);
            acc[2][2] = fmaf(a2, b2, acc[2][2]); acc[2][3] = fmaf(a2, b3, acc[2][3]);
            acc[3][0] = fmaf(a3, b0, acc[3][0]); acc[3][1] = fmaf(a3, b1, acc[3][1]);
            acc[3][2] = fmaf(a3, b2, acc[3][2]); acc[3][3] = fmaf(a3, b3, acc[3][3]);
        }
    }
#pragma unroll
    for (int i = 0; i < 4; ++i) {
        int r = row0 + ty * 4 + i;
        if (r >= M) continue;
#pragma unroll
        for (int j = 0; j < 4; ++j) {
            int c = col0 + tx * 4 + j;
            float v = alpha * acc[i][j] + ((bptr && ks == 0) ? bptr[c] : 0.f);
            if (nks > 1) atomicAdd(&C[(size_t)r * ldc + c], v);
            else C[(size_t)r * ldc + c] = v;
        }
    }
}

// ---------- fused Ge/Ee: z=0 -> Ge = gbuf @ rg_w1[:1024], z=1 -> Ee = emb @ rg_w1[1024:] ----------
__global__ __launch_bounds__(256) void sgemm_ge_ee_kernel(
    const float* __restrict__ gbuf, const float* __restrict__ emb,
    const float* __restrict__ rg_w1, float* __restrict__ Ge, float* __restrict__ Ee)
{
    const int z = blockIdx.z;
    const float* A = z ? emb : gbuf;
    const float* Bm = rg_w1 + (size_t)z * 1048576;
    float* C = z ? Ee : Ge;
    const int M = z ? 64 : 16;
    const int nks = 8, Kc = 128;
    const int ks = blockIdx.x % nks;
    __shared__ float As[64 * 36];
    __shared__ float Bs[32 * 68];
    const int tid = threadIdx.x;
    const int col0 = blockIdx.y * 64;
    const int ty = tid >> 4, tx = tid & 15;
    float acc[4][4] = {};
    const int aflat = tid * 8;
    const int ar = aflat >> 5, ac = aflat & 31;
    const int br = aflat >> 6, bc = aflat & 63;
    for (int k0 = ks * Kc; k0 < (ks + 1) * Kc; k0 += 32) {
        __syncthreads();
        float4 va0 = make_float4(0.f, 0.f, 0.f, 0.f), va1 = va0;
        if (ar < M) {
            const float* src = A + (size_t)ar * 1024 + k0 + ac;
            va0 = *(const float4*)src;
            va1 = *(const float4*)(src + 4);
        }
        *(float4*)&As[ar * 36 + ac] = va0;
        *(float4*)&As[ar * 36 + ac + 4] = va1;
        {
            const float* srcb = Bm + (size_t)(k0 + br) * 1024 + col0 + bc;
            *(float4*)&Bs[br * 68 + bc] = *(const float4*)srcb;
            *(float4*)&Bs[br * 68 + bc + 4] = *(const float4*)(srcb + 4);
        }
        __syncthreads();
#pragma unroll
        for (int kk = 0; kk < 32; ++kk) {
            float a0 = As[(ty * 4 + 0) * 36 + kk];
            float a1 = As[(ty * 4 + 1) * 36 + kk];
            float a2 = As[(ty * 4 + 2) * 36 + kk];
            float a3 = As[(ty * 4 + 3) * 36 + kk];
            float b0 = Bs[kk * 68 + tx * 4 + 0];
            float b1 = Bs[kk * 68 + tx * 4 + 1];
            float b2 = Bs[kk * 68 + tx * 4 + 2];
            float b3 = Bs[kk * 68 + tx * 4 + 3];
            acc[0][0] = fmaf(a0, b0, acc[0][0]); acc[0][1] = fmaf(a0, b1, acc[0][1]);
            acc[0][2] = fmaf(a0, b2, acc[0][2]); acc[0][3] = fmaf(a0, b3, acc[0][3]);
            acc[1][0] = fmaf(a1, b0, acc[1][0]); acc[1][1] = fmaf(a1, b1, acc[1][1]);
            acc[1][2] = fmaf(a1, b2, acc[1][2]); acc[1][3] = fmaf(a1, b3, acc[1][3]);
            acc[2][0] = fmaf(a2, b0, acc[2][0]); acc[2][1] = fmaf(a2, b1, acc[2][1]);
            acc[2][2] = fmaf(a2, b2, acc[2][2]); acc[2][3] = fmaf(a2, b3, acc[2][3]);
            acc[3][0] = fmaf(a3, b0, acc[3][0]); acc[3][1] = fmaf(a3, b1, acc[3][1]);
            acc[3][2] = fmaf(a3, b2, acc[3][2]); acc[3][3] = fmaf(a3, b3, acc[3][3]);
        }
    }
#pragma unroll
    for (int i = 0; i < 4; ++i) {
        int r = ty * 4 + i;
        if (r >= M) continue;
#pragma unroll
        for (int j = 0; j < 4; ++j) {
            int c = col0 + tx * 4 + j;
            atomicAdd(&C[(size_t)r * 1024 + c], acc[i][j]);
        }
    }
}

// ---------- fused gate: h1=tanh -> logits -> softmax -> DR = rw @ emb ----------
__global__ __launch_bounds__(256) void gate_kernel(
    const float* __restrict__ Ge, const float* __restrict__ Ee, const float* __restrict__ rg_b1,
    const float* __restrict__ rg_w2, const float* __restrict__ rg_b2,
    const float* __restrict__ emb, float* __restrict__ DR)
{
    const int row = blockIdx.x;       // 1024 = b*64+n
    const int b = row >> 6, n = row & 63;
    __shared__ float h[1024];
    __shared__ float red[256];
    __shared__ float rw[64];
    const int tid = threadIdx.x;
    for (int c = tid; c < 1024; c += 256)
        h[c] = tanhf(Ge[b * 1024 + c] + Ee[n * 1024 + c] + rg_b1[c]);
    __syncthreads();
    const int j = tid & 63, ch = tid >> 6;
    float part = 0.f;
    const float* w2p = rg_w2 + (size_t)(ch * 256) * 64 + j;
    for (int c = 0; c < 256; ++c)
        part = fmaf(h[ch * 256 + c], w2p[c * 64], part);
    red[tid] = part;
    __syncthreads();
    if (tid < 64) {
        float lg = red[tid] + red[tid + 64] + red[tid + 128] + red[tid + 192] + rg_b2[j];
        float m = lg;
#pragma unroll
        for (int off = 1; off < 64; off <<= 1) m = fmaxf(m, __shfl_xor(m, off, 64));
        float e = __expf(lg - m);
        float s = e;
#pragma unroll
        for (int off = 1; off < 64; off <<= 1) s += __shfl_xor(s, off, 64);
        rw[tid] = e / s;
    }
    __syncthreads();
    float4 acc = make_float4(0.f, 0.f, 0.f, 0.f);
    const float4* E4 = (const float4*)emb;
    for (int nn = 0; nn < 64; ++nn) {
        float wv = rw[nn];
        float4 ev = E4[nn * 256 + tid];
        acc.x = fmaf(wv, ev.x, acc.x);
        acc.y = fmaf(wv, ev.y, acc.y);
        acc.z = fmaf(wv, ev.z, acc.z);
        acc.w = fmaf(wv, ev.w, acc.w);
    }
    *(float4*)&DR[(size_t)row * 1024 + tid * 4] = acc;
}

// ---------- fused per-device heads: W1 GEMM + ReLU + W2 dot + activation ----------
// Replaces heads_p1 + heads_p2 + the 16MB hpart round-trip. Grid (64 n, 2 task,
// 4 b-quads). 256 threads: j = tid&127 (hidden), sub = tid>>7 (K-half).
__global__ __launch_bounds__(256) void heads_kernel(
    const float* __restrict__ g, const float* __restrict__ DR,
    const float* __restrict__ rw1, const float* __restrict__ cw1,
    const float* __restrict__ rb1, const float* __restrict__ rw2, const float* __restrict__ rb2,
    const float* __restrict__ cb1, const float* __restrict__ cw2, const float* __restrict__ cb2,
    float* __restrict__ out)
{
    const int n = blockIdx.x, task = blockIdx.y, bq = blockIdx.z;
    __shared__ float comb[4][1024];
    __shared__ float apart[2][4][128];
    const int tid = threadIdx.x;
#pragma unroll
    for (int i = 0; i < 4; ++i) {
        int idx = tid + i * 256;               // 1024 float4 loads
        int bb = idx >> 8, c4 = idx & 255;
        int b = bq * 4 + bb;
        float4 gv = *(const float4*)&g[b * 1024 + c4 * 4];
        float4 dv = *(const float4*)&DR[((size_t)(b * 64 + n)) * 1024 + c4 * 4];
        *(float4*)&comb[bb][c4 * 4] = make_float4(gv.x + dv.x, gv.y + dv.y, gv.z + dv.z, gv.w + dv.w);
    }
    __syncthreads();
    const int j = tid & 127, sub = tid >> 7;
    const float* W1 = (task ? cw1 : rw1) + (size_t)n * 131072 + (size_t)sub * 512 * 128 + j;
    float a[4] = {};
    for (int c4 = 0; c4 < 128; ++c4) {
        const int cb = sub * 512 + c4 * 4;
        const float w0 = W1[(c4 * 4 + 0) * 128];
        const float w1 = W1[(c4 * 4 + 1) * 128];
        const float w2 = W1[(c4 * 4 + 2) * 128];
        const float w3 = W1[(c4 * 4 + 3) * 128];
#pragma unroll
        for (int bb = 0; bb < 4; ++bb) {
            float4 cv = *(const float4*)&comb[bb][cb];
            a[bb] = fmaf(cv.x, w0, a[bb]);
            a[bb] = fmaf(cv.y, w1, a[bb]);
            a[bb] = fmaf(cv.z, w2, a[bb]);
            a[bb] = fmaf(cv.w, w3, a[bb]);
        }
    }
#pragma unroll
    for (int bb = 0; bb < 4; ++bb) apart[sub][bb][j] = a[bb];
    __syncthreads();
    const int wv = tid >> 6, lane = tid & 63;  // wave wv handles b = bq*4+wv
    const float* b1 = (task ? cb1 : rb1) + n * 128;
    const float* W2 = (task ? cw2 : rw2) + n * 128;
    float h1 = b1[lane]      + apart[0][wv][lane]      + apart[1][wv][lane];
    float h2 = b1[lane + 64] + apart[0][wv][lane + 64] + apart[1][wv][lane + 64];
    float s = fmaxf(h1, 0.f) * W2[lane] + fmaxf(h2, 0.f) * W2[lane + 64];
#pragma unroll
    for (int off = 1; off < 64; off <<= 1) s += __shfl_xor(s, off, 64);
    if (lane == 0) {
        s += (task ? cb2 : rb2)[n];
        float r = task ? (1.f / (1.f + __expf(-s)))
                       : (fmaxf(s, 0.f) + log1pf(__expf(-fabsf(s))));
        out[task * 1024 + (bq * 4 + wv) * 64 + n] = r;
    }
}

// ---------- launch ----------
extern "C" void kernel_launch(void* const* d_in, const int* in_sizes, int n_in,
                              void* d_out, int out_size, void* d_ws, size_t ws_size,
                              hipStream_t stream)
{
    const float* x      = (const float*)d_in[0];
    const float* wq     = (const float*)d_in[1];
    const float* bq     = (const float*)d_in[2];
    const float* wk     = (const float*)d_in[3];
    const float* bk     = (const float*)d_in[4];
    const float* wv     = (const float*)d_in[5];
    const float* bv     = (const float*)d_in[6];
    const float* wo     = (const float*)d_in[7];
    const float* bo     = (const float*)d_in[8];
    const float* emb    = (const float*)d_in[9];
    const float* rg_w1  = (const float*)d_in[10];
    const float* rg_b1  = (const float*)d_in[11];
    const float* rg_w2  = (const float*)d_in[12];
    const float* rg_b2  = (const float*)d_in[13];
    const float* reg_w1 = (const float*)d_in[14];
    const float* reg_b1 = (const float*)d_in[15];
    const float* reg_w2 = (const float*)d_in[16];
    const float* reg_b2 = (const float*)d_in[17];
    const float* cls_w1 = (const float*)d_in[18];
    const float* cls_b1 = (const float*)d_in[19];
    const float* cls_w2 = (const float*)d_in[20];
    const float* cls_b2 = (const float*)d_in[21];

    char* ws = (char*)d_ws;
    size_t off = 0;
    auto alloc = [&](size_t bytes) { size_t cur = off; off += (bytes + 255) & ~(size_t)255; return cur; };

    ushort_t* xb  = (ushort_t*)(ws + alloc((size_t)16777216 * 2));
    ushort_t* wqT = (ushort_t*)(ws + alloc((size_t)1048576 * 2));
    ushort_t* wkT = (ushort_t*)(ws + alloc((size_t)1048576 * 2));
    ushort_t* Qb  = (ushort_t*)(ws + alloc((size_t)16777216 * 2));
    ushort_t* Kb  = (ushort_t*)(ws + alloc((size_t)16777216 * 2));
    size_t zero_beg = off;
    float* wcol = (float*)(ws + alloc((size_t)131072 * 4));
    float* cm   = (float*)(ws + alloc((size_t)16384 * 4));
    float* gbuf = (float*)(ws + alloc((size_t)16384 * 4));
    float* Ge   = (float*)(ws + alloc((size_t)16384 * 4));
    float* Ee   = (float*)(ws + alloc((size_t)65536 * 4));
    size_t zero_end = off;
    float* u    = (float*)(ws + alloc((size_t)131072 * 4));   // fully overwritten, no memset
    float* DR   = (float*)(ws + alloc((size_t)1048576 * 4));

    hipMemsetAsync(ws + zero_beg, 0, zero_end - zero_beg, stream);

    prep_tr_kernel<<<8704, 256, 0, stream>>>(x, xb, wq, wk, wqT, wkT);
    gemm_qk_kernel<<<dim3(128, 8), 512, 0, stream>>>(xb, wqT, wkT, bq, bk, Qb, Kb);
    attn_mfma_kernel<<<dim3(128, 4), 512, 0, stream>>>(Qb, Kb, wcol);
    u_kernel<<<dim3(16, 16), 256, 0, stream>>>(xb, wcol, u);
    sgemm_kernel<<<dim3(8, 2, 8), 256, 0, stream>>>(u, 8192, 1024, wv, 1024, 128, bv, 128,
                                                    cm, 1024, 128, 16, 128, 1024, 1.f / 1024.f, 8);
    sgemm_kernel<<<dim3(8, 16, 1), 256, 0, stream>>>(cm, 1024, 0, wo, 1024, 0, bo, 0,
                                                     gbuf, 1024, 0, 16, 1024, 1024, 1.f, 8);
    sgemm_ge_ee_kernel<<<dim3(8, 16, 2), 256, 0, stream>>>(gbuf, emb, rg_w1, Ge, Ee);
    gate_kernel<<<1024, 256, 0, stream>>>(Ge, Ee, rg_b1, rg_w2, rg_b2, emb, DR);
    heads_kernel<<<dim3(64, 2, 4), 256, 0, stream>>>(gbuf, DR, reg_w1, cls_w1,
                                                     reg_b1, reg_w2, reg_b2,
                                                     cls_b1, cls_w2, cls_b2, (float*)d_out);
    (void)in_sizes; (void)n_in; (void)out_size; (void)ws_size;
}

// Round 7
// 451.625 us; speedup vs baseline: 1.1494x; 1.0026x over previous
//
#include <hip/hip_runtime.h>

typedef unsigned short ushort_t;
typedef __attribute__((ext_vector_type(8))) short short8;
typedef __attribute__((ext_vector_type(4))) float floatx4;

// ---------- helpers ----------
__device__ __forceinline__ ushort_t f2bf(float f) {
    unsigned u = __float_as_uint(f);
    return (ushort_t)((u + 0x7fffu + ((u >> 16) & 1u)) >> 16);
}
__device__ __forceinline__ void gll16(const void* g, void* l) {
    __builtin_amdgcn_global_load_lds(
        (const __attribute__((address_space(1))) unsigned int*)g,
        (__attribute__((address_space(3))) unsigned int*)l, 16, 0, 0);
}
#if __has_builtin(__builtin_amdgcn_exp2f)
#define EXP2f(x) __builtin_amdgcn_exp2f(x)
#else
#define EXP2f(x) exp2f(x)
#endif

// NOTE (journal): R4 4-deep counted-vmcnt gemm pipeline REGRESSED (120us).
// R6 cooperative-tail (hipLaunchCooperativeKernel) FAILED: out=all-zero
// (absmax 0.711 = max|ref|) — coop launch appears to no-op under the
// harness launch path. Do not re-add either.

// ---------- shared device GEMM tile body (64-col x M-row, split-K atomic) ----------
__device__ __forceinline__ void sgemm_body(
    const float* __restrict__ A, int lda, const float* __restrict__ Bm, int ldb,
    const float* __restrict__ bias, float* __restrict__ C, int ldc,
    int M, int Kc, int ks, int col0, float alpha,
    int tid, float* As, float* Bs)
{
    const int ty = tid >> 4, tx = tid & 15;
    float acc[4][4] = {};
    const int aflat = tid * 8;
    const int ar = aflat >> 5, ac = aflat & 31;
    const int br = aflat >> 6, bc = aflat & 63;
    for (int k0 = ks * Kc; k0 < (ks + 1) * Kc; k0 += 32) {
        __syncthreads();
        float4 va0 = make_float4(0.f, 0.f, 0.f, 0.f), va1 = va0;
        if (ar < M) {
            const float* src = A + (size_t)ar * lda + k0 + ac;
            va0 = *(const float4*)src;
            va1 = *(const float4*)(src + 4);
        }
        *(float4*)&As[ar * 36 + ac] = va0;
        *(float4*)&As[ar * 36 + ac + 4] = va1;
        {
            const float* srcb = Bm + (size_t)(k0 + br) * ldb + col0 + bc;
            *(float4*)&Bs[br * 68 + bc] = *(const float4*)srcb;
            *(float4*)&Bs[br * 68 + bc + 4] = *(const float4*)(srcb + 4);
        }
        __syncthreads();
#pragma unroll
        for (int kk = 0; kk < 32; ++kk) {
            float a0 = As[(ty * 4 + 0) * 36 + kk];
            float a1 = As[(ty * 4 + 1) * 36 + kk];
            float a2 = As[(ty * 4 + 2) * 36 + kk];
            float a3 = As[(ty * 4 + 3) * 36 + kk];
            float b0 = Bs[kk * 68 + tx * 4 + 0];
            float b1 = Bs[kk * 68 + tx * 4 + 1];
            float b2 = Bs[kk * 68 + tx * 4 + 2];
            float b3 = Bs[kk * 68 + tx * 4 + 3];
            acc[0][0] = fmaf(a0, b0, acc[0][0]); acc[0][1] = fmaf(a0, b1, acc[0][1]);
            acc[0][2] = fmaf(a0, b2, acc[0][2]); acc[0][3] = fmaf(a0, b3, acc[0][3]);
            acc[1][0] = fmaf(a1, b0, acc[1][0]); acc[1][1] = fmaf(a1, b1, acc[1][1]);
            acc[1][2] = fmaf(a1, b2, acc[1][2]); acc[1][3] = fmaf(a1, b3, acc[1][3]);
            acc[2][0] = fmaf(a2, b0, acc[2][0]); acc[2][1] = fmaf(a2, b1, acc[2][1]);
            acc[2][2] = fmaf(a2, b2, acc[2][2]); acc[2][3] = fmaf(a2, b3, acc[2][3]);
            acc[3][0] = fmaf(a3, b0, acc[3][0]); acc[3][1] = fmaf(a3, b1, acc[3][1]);
            acc[3][2] = fmaf(a3, b2, acc[3][2]); acc[3][3] = fmaf(a3, b3, acc[3][3]);
        }
    }
#pragma unroll
    for (int i = 0; i < 4; ++i) {
        int r = ty * 4 + i;
        if (r >= M) continue;
#pragma unroll
        for (int j = 0; j < 4; ++j) {
            int c = col0 + tx * 4 + j;
            float v = alpha * acc[i][j] + ((bias && ks == 0) ? bias[c] : 0.f);
            atomicAdd(&C[(size_t)r * ldc + c], v);
        }
    }
}

// ---------- fused: cast x->bf16 + transpose wq/wk + Ee = emb @ rg_w1[1024:] ----------
__global__ __launch_bounds__(256) void prep_tr_kernel(
    const float* __restrict__ x, ushort_t* __restrict__ xb,
    const float* __restrict__ wq, const float* __restrict__ wk,
    ushort_t* __restrict__ wqT, ushort_t* __restrict__ wkT,
    const float* __restrict__ emb, const float* __restrict__ rg_w1, float* __restrict__ Ee)
{
    __shared__ __align__(16) char psm[18432];
    const int bid = blockIdx.x;
    const int tid = threadIdx.x;
    if (bid < 8192) {
        size_t i = ((size_t)bid * 256 + tid) * 8;
        float4 v0 = *(const float4*)(x + i);
        float4 v1 = *(const float4*)(x + i + 4);
        uint4 o;
        o.x = (unsigned)f2bf(v0.x) | ((unsigned)f2bf(v0.y) << 16);
        o.y = (unsigned)f2bf(v0.z) | ((unsigned)f2bf(v0.w) << 16);
        o.z = (unsigned)f2bf(v1.x) | ((unsigned)f2bf(v1.y) << 16);
        o.w = (unsigned)f2bf(v1.z) | ((unsigned)f2bf(v1.w) << 16);
        *(uint4*)(xb + i) = o;
        return;
    }
    if (bid < 8704) {
        float (*t)[65] = (float(*)[65])psm;
        const int b2 = bid - 8192;               // 0..511
        const int bx = b2 & 15, by = (b2 >> 4) & 15, bz = b2 >> 8;
        const float* src = bz ? wk : wq;
        ushort_t* dst = bz ? wkT : wqT;
        const int k0 = bx * 64, n0 = by * 64;
        const int rr = tid >> 4, cc = (tid & 15) * 4;
#pragma unroll
        for (int p = 0; p < 4; ++p) {
            float4 v = *(const float4*)(src + (size_t)(k0 + p * 16 + rr) * 1024 + n0 + cc);
            t[p * 16 + rr][cc + 0] = v.x;
            t[p * 16 + rr][cc + 1] = v.y;
            t[p * 16 + rr][cc + 2] = v.z;
            t[p * 16 + rr][cc + 3] = v.w;
        }
        __syncthreads();
#pragma unroll
        for (int p = 0; p < 4; ++p) {
            int nl = p * 16 + rr;
            uint2 o;
            o.x = (unsigned)f2bf(t[cc + 0][nl]) | ((unsigned)f2bf(t[cc + 1][nl]) << 16);
            o.y = (unsigned)f2bf(t[cc + 2][nl]) | ((unsigned)f2bf(t[cc + 3][nl]) << 16);
            *(uint2*)(dst + (size_t)(n0 + nl) * 1024 + k0 + cc) = o;
        }
        return;
    }
    // Ee units: 128 blocks, exactly-once read of rg_w1[1024:], off the critical path
    float* As = (float*)psm;
    float* Bs = As + 64 * 36;
    const int bx2 = bid - 8704;                  // 0..127
    const int ks = bx2 & 7, coly = bx2 >> 3;
    sgemm_body(emb, 1024, rg_w1 + (size_t)1048576, 1024, nullptr,
               Ee, 1024, 64, 128, ks, coly * 64, 1.f, tid, As, Bs);
}

// ---------- MFMA bf16 GEMM: Q and K fused per block, shared A-tile ----------
// R3/R5-verified 2-phase structure (~79-93 us).
__global__ __launch_bounds__(512, 4) void gemm_qk_kernel(
    const ushort_t* __restrict__ xb, const ushort_t* __restrict__ wqT, const ushort_t* __restrict__ wkT,
    const float* __restrict__ bq, const float* __restrict__ bk,
    ushort_t* __restrict__ Qb, ushort_t* __restrict__ Kb)
{
    const int bm = blockIdx.x;          // 128 M-tiles of 128
    const int bn = blockIdx.y;          // 8 N-tiles of 128

    __shared__ ushort_t a_lds[2][128 * 32];    // 2 x 8 KB
    __shared__ ushort_t q_lds[2][128 * 32];
    __shared__ ushort_t k_lds[2][128 * 32];

    const int tid = threadIdx.x;
    const int lane = tid & 63;
    const int wave = tid >> 6;          // 0..7
    const int wmat = wave >> 2;         // 0=Q, 1=K
    const int wr = (wave >> 1) & 1, wc = wave & 1;
    const int l16 = lane & 15, quad = lane >> 4;
    const int qs = quad ^ ((l16 >> 1) & 3);   // swizzled chunk for fragment reads

    floatx4 acc[4][4];
    const floatx4 zero4 = {0.f, 0.f, 0.f, 0.f};
#pragma unroll
    for (int i = 0; i < 4; ++i)
#pragma unroll
        for (int j = 0; j < 4; ++j) acc[i][j] = zero4;

    const int srow = tid >> 2;
    const int skof = ((tid & 3) ^ ((tid >> 3) & 3)) * 8;
    const ushort_t* gA = xb + (size_t)(bm * 128 + srow) * 1024 + skof;
    const ushort_t* gQ = wqT + (size_t)(bn * 128 + srow) * 1024 + skof;
    const ushort_t* gK = wkT + (size_t)(bn * 128 + srow) * 1024 + skof;

    auto issue = [&](int buf, int k0) {
        gll16(gA + k0, &a_lds[buf][wave * 512]);
        gll16(gQ + k0, &q_lds[buf][wave * 512]);
        gll16(gK + k0, &k_lds[buf][wave * 512]);
    };

    const ushort_t* lbase = wmat ? k_lds[0] : q_lds[0];
    const int lstride = wmat ? (int)(k_lds[1] - k_lds[0]) : (int)(q_lds[1] - q_lds[0]);

    auto compute = [&](int buf) {
        const ushort_t* la = a_lds[buf];
        const ushort_t* lb = lbase + buf * lstride;
        short8 afr[4], bfr[4];
#pragma unroll
        for (int mi = 0; mi < 4; ++mi)
            afr[mi] = *(const short8*)&la[(wr * 64 + mi * 16 + l16) * 32 + qs * 8];
#pragma unroll
        for (int ni = 0; ni < 4; ++ni)
            bfr[ni] = *(const short8*)&lb[(wc * 64 + ni * 16 + l16) * 32 + qs * 8];
#pragma unroll
        for (int mi = 0; mi < 4; ++mi)
#pragma unroll
            for (int ni = 0; ni < 4; ++ni)
                acc[mi][ni] = __builtin_amdgcn_mfma_f32_16x16x32_bf16(afr[mi], bfr[ni], acc[mi][ni], 0, 0, 0);
    };

    issue(0, 0);
#pragma unroll 4
    for (int kt = 0; kt < 31; ++kt) {
        __syncthreads();
        issue((kt + 1) & 1, (kt + 1) * 32);
        compute(kt & 1);
    }
    __syncthreads();
    compute(1);

    ushort_t* Out = wmat ? Kb : Qb;
    const float* bias = wmat ? bk : bq;
    // Q postscale = log2(e)/sqrt(128): attention uses exp2 directly.
    const float postscale = wmat ? 1.0f : 0.12751744900508692f;

    const int bq_ = bm >> 3;
    const int sb = (bm & 7) * 128 + wr * 64 + quad * 4;
    const int dc = wc * 64 + l16;
    float bp[4];
#pragma unroll
    for (int ni = 0; ni < 4; ++ni) bp[ni] = bias[bn * 128 + dc + ni * 16] * postscale;
    ushort_t* ob = Out + ((size_t)(bq_ * 8 + bn) * 1024 + sb) * 128 + dc;
#pragma unroll
    for (int mi = 0; mi < 4; ++mi)
#pragma unroll
        for (int ni = 0; ni < 4; ++ni) {
            ushort_t* p = ob + mi * 2048 + ni * 16;
#pragma unroll
            for (int r = 0; r < 4; ++r)
                p[r * 128] = f2bf(fmaf(acc[mi][ni][r], postscale, bp[ni]));
        }
}

// ---------- attention column sums via MFMA, QBLK=256, 8 waves share K-tile ----------
__global__ __launch_bounds__(512, 4) void attn_mfma_kernel(
    const ushort_t* __restrict__ Qb,   // [bh][1024][128] bf16 (exp2-scaled)
    const ushort_t* __restrict__ Kb,   // [bh][1024][128] bf16
    float* __restrict__ wout)          // [bh][1024], zero-init
{
    const int bh = blockIdx.x;         // 128
    const int qt = blockIdx.y;         // 4 q-tiles of 256 rows
    __shared__ ushort_t ks[2][64 * 128]; // 2 x 16 KB, XOR-swizzled 16B granules

    const int tid = threadIdx.x;
    const int wave = tid >> 6, lane = tid & 63;
    const int l16 = lane & 15, quad = lane >> 4;

    const ushort_t* Ksrc = Kb + (size_t)bh * 1024 * 128;

    int srcoff[2];
#pragma unroll
    for (int c = 0; c < 2; ++c) {
        int r = c * 32 + (tid >> 4);
        int g = (tid & 15) ^ (r & 15);
        srcoff[c] = r * 128 + g * 8;
    }

    auto issue = [&](int buf, int kt) {
        const ushort_t* src = Ksrc + (size_t)kt * 8192;
#pragma unroll
        for (int c = 0; c < 2; ++c)
            gll16(src + srcoff[c], &ks[buf][c * 4096 + wave * 512]);
    };

    short8 aq[2][4];
    {
        const ushort_t* qsrc = Qb + ((size_t)bh * 1024 + qt * 256 + wave * 32) * 128;
#pragma unroll
        for (int mi = 0; mi < 2; ++mi)
#pragma unroll
            for (int ksp = 0; ksp < 4; ++ksp)
                aq[mi][ksp] = *(const short8*)(qsrc + (size_t)(mi * 16 + l16) * 128 + ksp * 32 + quad * 8);
    }

    const floatx4 zero4 = {0.f, 0.f, 0.f, 0.f};
    float lsum[2][4];
#pragma unroll
    for (int mi = 0; mi < 2; ++mi)
#pragma unroll
        for (int r = 0; r < 4; ++r) lsum[mi][r] = 0.f;

    issue(0, 0);

    for (int kt = 0; kt < 16; ++kt) {
        __syncthreads();
        if (kt < 15) issue((kt + 1) & 1, kt + 1);
        const ushort_t* kbuf = ks[kt & 1];
        floatx4 acc[2][4];
#pragma unroll
        for (int mi = 0; mi < 2; ++mi)
#pragma unroll
            for (int ni = 0; ni < 4; ++ni) acc[mi][ni] = zero4;
#pragma unroll
        for (int ksp = 0; ksp < 4; ++ksp) {
            short8 bk[4];
#pragma unroll
            for (int ni = 0; ni < 4; ++ni) {
                int n = ni * 16 + l16;
                int gs = (ksp * 4 + quad) ^ (n & 15);
                bk[ni] = *(const short8*)&kbuf[n * 128 + gs * 8];
            }
#pragma unroll
            for (int mi = 0; mi < 2; ++mi)
#pragma unroll
                for (int ni = 0; ni < 4; ++ni)
                    acc[mi][ni] = __builtin_amdgcn_mfma_f32_16x16x32_bf16(aq[mi][ksp], bk[ni], acc[mi][ni], 0, 0, 0);
        }
#pragma unroll
        for (int mi = 0; mi < 2; ++mi)
#pragma unroll
            for (int r = 0; r < 4; ++r) {
                float s = 0.f;
#pragma unroll
                for (int ni = 0; ni < 4; ++ni) s += EXP2f(acc[mi][ni][r]);
                lsum[mi][r] += s;
            }
    }

    issue(0, 0);    // prefetch pass-2 tile 0

    float invl[2][4];
#pragma unroll
    for (int mi = 0; mi < 2; ++mi)
#pragma unroll
        for (int r = 0; r < 4; ++r) {
            float s = lsum[mi][r];
#pragma unroll
            for (int off = 1; off < 16; off <<= 1) s += __shfl_xor(s, off, 16);
            invl[mi][r] = 1.f / s;
        }

    for (int kt = 0; kt < 16; ++kt) {
        __syncthreads();
        if (kt < 15) issue((kt + 1) & 1, kt + 1);
        const ushort_t* kbuf = ks[kt & 1];
        floatx4 acc[2][4];
#pragma unroll
        for (int mi = 0; mi < 2; ++mi)
#pragma unroll
            for (int ni = 0; ni < 4; ++ni) acc[mi][ni] = zero4;
#pragma unroll
        for (int ksp = 0; ksp < 4; ++ksp) {
            short8 bk[4];
#pragma unroll
            for (int ni = 0; ni < 4; ++ni) {
                int n = ni * 16 + l16;
                int gs = (ksp * 4 + quad) ^ (n & 15);
                bk[ni] = *(const short8*)&kbuf[n * 128 + gs * 8];
            }
#pragma unroll
            for (int mi = 0; mi < 2; ++mi)
#pragma unroll
                for (int ni = 0; ni < 4; ++ni)
                    acc[mi][ni] = __builtin_amdgcn_mfma_f32_16x16x32_bf16(aq[mi][ksp], bk[ni], acc[mi][ni], 0, 0, 0);
        }
#pragma unroll
        for (int ni = 0; ni < 4; ++ni) {
            float s = 0.f;
#pragma unroll
            for (int mi = 0; mi < 2; ++mi)
#pragma unroll
                for (int r = 0; r < 4; ++r)
                    s += EXP2f(acc[mi][ni][r]) * invl[mi][r];
            s += __shfl_xor(s, 16, 64);
            s += __shfl_xor(s, 32, 64);
            if (quad == 0) atomicAdd(&wout[bh * 1024 + kt * 64 + ni * 16 + l16], s);
        }
    }
}

// ---------- u[b,h,:] = sum_k w[b,h,k] * xb[b,k,:]  — no atomics ----------
__global__ __launch_bounds__(256) void u_kernel(const ushort_t* __restrict__ xb,
                                                const float* __restrict__ w,
                                                float* __restrict__ u)
{
    const int b = blockIdx.x, dc = blockIdx.y;
    const int tid = threadIdx.x;
    const int kp = tid >> 4, dli = tid & 15;
    const int d0 = dc * 64;
    __shared__ float4 accl[16][8][16];     // 32 KB

    float4 acc[8];
#pragma unroll
    for (int h = 0; h < 8; ++h) acc[h] = make_float4(0.f, 0.f, 0.f, 0.f);

    const ushort_t* Xp = xb + ((size_t)(b * 1024 + kp * 64)) * 1024 + d0 + dli * 4;
    const float* wb = w + b * 8192 + kp * 64;
    for (int k = 0; k < 64; ++k) {
        uint2 uv = *(const uint2*)(Xp + (size_t)k * 1024);
        float x0 = __uint_as_float(uv.x << 16);
        float x1 = __uint_as_float(uv.x & 0xffff0000u);
        float x2 = __uint_as_float(uv.y << 16);
        float x3 = __uint_as_float(uv.y & 0xffff0000u);
#pragma unroll
        for (int h = 0; h < 8; ++h) {
            float ww = wb[h * 1024 + k];
            acc[h].x = fmaf(ww, x0, acc[h].x);
            acc[h].y = fmaf(ww, x1, acc[h].y);
            acc[h].z = fmaf(ww, x2, acc[h].z);
            acc[h].w = fmaf(ww, x3, acc[h].w);
        }
    }
#pragma unroll
    for (int h = 0; h < 8; ++h) accl[kp][h][dli] = acc[h];
    __syncthreads();
    if (tid < 128) {
        const int h = tid >> 4, di = tid & 15;
        float4 s = accl[0][h][di];
#pragma unroll
        for (int k2 = 1; k2 < 16; ++k2) {
            float4 v = accl[k2][h][di];
            s.x += v.x; s.y += v.y; s.z += v.z; s.w += v.w;
        }
        *(float4*)&u[((size_t)(b * 8 + h)) * 1024 + d0 + di * 4] = s;
    }
}

// ---------- small GEMM with split-K ----------
__global__ __launch_bounds__(256) void sgemm_kernel(
    const float* __restrict__ A, int lda, long sAz,
    const float* __restrict__ Bm, int ldb, long sBz,
    const float* __restrict__ bias, long sBiasz,
    float* __restrict__ C, int ldc, long sCz,
    int M, int N, int K, float alpha, int nks)
{
    const int z = blockIdx.z;
    const int ks = blockIdx.x % nks;
    const int mt = blockIdx.x / nks;
    const int Kc = K / nks;
    A += (size_t)z * sAz;
    Bm += (size_t)z * sBz;
    C += (size_t)z * sCz;
    const float* bptr = bias ? bias + (size_t)z * sBiasz : nullptr;
    __shared__ float As[64 * 36];
    __shared__ float Bs[32 * 68];
    const int tid = threadIdx.x;
    const int row0 = mt * 64, col0 = blockIdx.y * 64;
    const int ty = tid >> 4, tx = tid & 15;
    float acc[4][4] = {};
    const int aflat = tid * 8;
    const int ar = aflat >> 5, ac = aflat & 31;
    const int br = aflat >> 6, bc = aflat & 63;
    for (int k0 = ks * Kc; k0 < (ks + 1) * Kc; k0 += 32) {
        __syncthreads();
        float4 va0 = make_float4(0.f, 0.f, 0.f, 0.f), va1 = va0;
        if (row0 + ar < M) {
            const float* src = A + (size_t)(row0 + ar) * lda + k0 + ac;
            va0 = *(const float4*)src;
            va1 = *(const float4*)(src + 4);
        }
        *(float4*)&As[ar * 36 + ac] = va0;
        *(float4*)&As[ar * 36 + ac + 4] = va1;
        {
            const float* srcb = Bm + (size_t)(k0 + br) * ldb + col0 + bc;
            *(float4*)&Bs[br * 68 + bc] = *(const float4*)srcb;
            *(float4*)&Bs[br * 68 + bc + 4] = *(const float4*)(srcb + 4);
        }
        __syncthreads();
#pragma unroll
        for (int kk = 0; kk < 32; ++kk) {
            float a0 = As[(ty * 4 + 0) * 36 + kk];
            float a1 = As[(ty * 4 + 1) * 36 + kk];
            float a2 = As[(ty * 4 + 2) * 36 + kk];
            float a3 = As[(ty * 4 + 3) * 36 + kk];
            float b0 = Bs[kk * 68 + tx * 4 + 0];
            float b1 = Bs[kk * 68 + tx * 4 + 1];
            float b2 = Bs[kk * 68 + tx * 4 + 2];
            float b3 = Bs[kk * 68 + tx * 4 + 3];
            acc[0][0] = fmaf(a0, b0, acc[0][0]); acc[0][1] = fmaf(a0, b1, acc[0][1]);
            acc[0][2] = fmaf(a0, b2, acc[0][2]); acc[0][3] = fmaf(a0, b3, acc[0][3]);
            acc[1][0] = fmaf(a1, b0, acc[1][0]); acc[1][1] = fmaf(a1, b1, acc[1][1]);
            acc[1][2] = fmaf(a1, b2, acc[1][2]); acc[1][3] = fmaf(a1, b3, acc[1][3]);
            acc[2][0] = fmaf(a2, b0, acc[2][0]); acc[2][1] = fmaf(a2, b1, acc[2][1]);
            acc[2][2] = fmaf(a2, b2, acc[2][2]); acc[2][3] = fmaf(a2, b3, acc[2][3]);
            acc[3][0] = fmaf(a3, b0, acc[3][0]); acc[3][1] = fmaf(a3, b1, acc[3][1]);
            acc[3][2] = fmaf(a3, b2, acc[3][2]); acc[3][3] = fmaf(a3, b3, acc[3][3]);
        }
    }
#pragma unroll
    for (int i = 0; i < 4; ++i) {
        int r = row0 + ty * 4 + i;
        if (r >= M) continue;
#pragma unroll
        for (int j = 0; j < 4; ++j) {
            int c = col0 + tx * 4 + j;
            float v = alpha * acc[i][j] + ((bptr && ks == 0) ? bptr[c] : 0.f);
            if (nks > 1) atomicAdd(&C[(size_t)r * ldc + c], v);
            else C[(size_t)r * ldc + c] = v;
        }
    }
}

// ---------- fused gate, 4 rows/block: tanh -> logits -> softmax -> DR = rw @ emb ----------
// 4 consecutive rows share batch b (row>>6): rg_w2 and emb values loaded once per
// 4 rows => gate traffic ~512MB -> ~128MB. Math identical per row.
__global__ __launch_bounds__(256) void gate_kernel(
    const float* __restrict__ Ge, const float* __restrict__ Ee, const float* __restrict__ rg_b1,
    const float* __restrict__ rg_w2, const float* __restrict__ rg_b2,
    const float* __restrict__ emb, float* __restrict__ DR)
{
    const int row0 = blockIdx.x * 4;          // 256 blocks x 4 rows
    const int b = row0 >> 6, n0 = row0 & 63;
    __shared__ float h[4][1024];
    __shared__ float red[4][256];
    __shared__ float rw[4][64];
    const int tid = threadIdx.x;
    for (int idx = tid; idx < 4096; idx += 256) {
        int rr = idx >> 10, c = idx & 1023;
        h[rr][c] = tanhf(Ge[b * 1024 + c] + Ee[(n0 + rr) * 1024 + c] + rg_b1[c]);
    }
    __syncthreads();
    const int j = tid & 63, ch = tid >> 6;
    float part[4] = {0.f, 0.f, 0.f, 0.f};
    const float* w2p = rg_w2 + (size_t)(ch * 256) * 64 + j;
    for (int c = 0; c < 256; ++c) {
        float w = w2p[c * 64];
#pragma unroll
        for (int rr = 0; rr < 4; ++rr)
            part[rr] = fmaf(h[rr][ch * 256 + c], w, part[rr]);
    }
#pragma unroll
    for (int rr = 0; rr < 4; ++rr) red[rr][tid] = part[rr];
    __syncthreads();
    if (tid < 64) {
#pragma unroll
        for (int rr = 0; rr < 4; ++rr) {
            float lg = red[rr][tid] + red[rr][tid + 64] + red[rr][tid + 128] + red[rr][tid + 192] + rg_b2[j];
            float m = lg;
#pragma unroll
            for (int off = 1; off < 64; off <<= 1) m = fmaxf(m, __shfl_xor(m, off, 64));
            float e = __expf(lg - m);
            float s = e;
#pragma unroll
            for (int off = 1; off < 64; off <<= 1) s += __shfl_xor(s, off, 64);
            rw[rr][tid] = e / s;
        }
    }
    __syncthreads();
    float4 acc[4];
#pragma unroll
    for (int rr = 0; rr < 4; ++rr) acc[rr] = make_float4(0.f, 0.f, 0.f, 0.f);
    const float4* E4 = (const float4*)emb;
    for (int nn = 0; nn < 64; ++nn) {
        float4 ev = E4[nn * 256 + tid];
#pragma unroll
        for (int rr = 0; rr < 4; ++rr) {
            float wv = rw[rr][nn];
            acc[rr].x = fmaf(wv, ev.x, acc[rr].x);
            acc[rr].y = fmaf(wv, ev.y, acc[rr].y);
            acc[rr].z = fmaf(wv, ev.z, acc[rr].z);
            acc[rr].w = fmaf(wv, ev.w, acc[rr].w);
        }
    }
#pragma unroll
    for (int rr = 0; rr < 4; ++rr)
        *(float4*)&DR[(size_t)(row0 + rr) * 1024 + tid * 4] = acc[rr];
}

// ---------- fused per-device heads: W1 GEMM + ReLU + W2 dot + activation ----------
// (R5-verified. Known cost: W1 slab read 4x via L3; acceptable at current scale.)
__global__ __launch_bounds__(256) void heads_kernel(
    const float* __restrict__ g, const float* __restrict__ DR,
    const float* __restrict__ rw1, const float* __restrict__ cw1,
    const float* __restrict__ rb1, const float* __restrict__ rw2, const float* __restrict__ rb2,
    const float* __restrict__ cb1, const float* __restrict__ cw2, const float* __restrict__ cb2,
    float* __restrict__ out)
{
    const int n = blockIdx.x, task = blockIdx.y, bq = blockIdx.z;
    __shared__ float comb[4][1024];
    __shared__ float apart[2][4][128];
    const int tid = threadIdx.x;
#pragma unroll
    for (int i = 0; i < 4; ++i) {
        int idx = tid + i * 256;               // 1024 float4 loads
        int bb = idx >> 8, c4 = idx & 255;
        int b = bq * 4 + bb;
        float4 gv = *(const float4*)&g[b * 1024 + c4 * 4];
        float4 dv = *(const float4*)&DR[((size_t)(b * 64 + n)) * 1024 + c4 * 4];
        *(float4*)&comb[bb][c4 * 4] = make_float4(gv.x + dv.x, gv.y + dv.y, gv.z + dv.z, gv.w + dv.w);
    }
    __syncthreads();
    const int j = tid & 127, sub = tid >> 7;
    const float* W1 = (task ? cw1 : rw1) + (size_t)n * 131072 + (size_t)sub * 512 * 128 + j;
    float a[4] = {};
    for (int c4 = 0; c4 < 128; ++c4) {
        const int cb = sub * 512 + c4 * 4;
        const float w0 = W1[(c4 * 4 + 0) * 128];
        const float w1 = W1[(c4 * 4 + 1) * 128];
        const float w2 = W1[(c4 * 4 + 2) * 128];
        const float w3 = W1[(c4 * 4 + 3) * 128];
#pragma unroll
        for (int bb = 0; bb < 4; ++bb) {
            float4 cv = *(const float4*)&comb[bb][cb];
            a[bb] = fmaf(cv.x, w0, a[bb]);
            a[bb] = fmaf(cv.y, w1, a[bb]);
            a[bb] = fmaf(cv.z, w2, a[bb]);
            a[bb] = fmaf(cv.w, w3, a[bb]);
        }
    }
#pragma unroll
    for (int bb = 0; bb < 4; ++bb) apart[sub][bb][j] = a[bb];
    __syncthreads();
    const int wv = tid >> 6, lane = tid & 63;  // wave wv handles b = bq*4+wv
    const float* b1 = (task ? cb1 : rb1) + n * 128;
    const float* W2 = (task ? cw2 : rw2) + n * 128;
    float h1 = b1[lane]      + apart[0][wv][lane]      + apart[1][wv][lane];
    float h2 = b1[lane + 64] + apart[0][wv][lane + 64] + apart[1][wv][lane + 64];
    float s = fmaxf(h1, 0.f) * W2[lane] + fmaxf(h2, 0.f) * W2[lane + 64];
#pragma unroll
    for (int off = 1; off < 64; off <<= 1) s += __shfl_xor(s, off, 64);
    if (lane == 0) {
        s += (task ? cb2 : rb2)[n];
        float r = task ? (1.f / (1.f + __expf(-s)))
                       : (fmaxf(s, 0.f) + log1pf(__expf(-fabsf(s))));
        out[task * 1024 + (bq * 4 + wv) * 64 + n] = r;
    }
}

// ---------- launch ----------
extern "C" void kernel_launch(void* const* d_in, const int* in_sizes, int n_in,
                              void* d_out, int out_size, void* d_ws, size_t ws_size,
                              hipStream_t stream)
{
    const float* x      = (const float*)d_in[0];
    const float* wq     = (const float*)d_in[1];
    const float* bq     = (const float*)d_in[2];
    const float* wk     = (const float*)d_in[3];
    const float* bk     = (const float*)d_in[4];
    const float* wv     = (const float*)d_in[5];
    const float* bv     = (const float*)d_in[6];
    const float* wo     = (const float*)d_in[7];
    const float* bo     = (const float*)d_in[8];
    const float* emb    = (const float*)d_in[9];
    const float* rg_w1  = (const float*)d_in[10];
    const float* rg_b1  = (const float*)d_in[11];
    const float* rg_w2  = (const float*)d_in[12];
    const float* rg_b2  = (const float*)d_in[13];
    const float* reg_w1 = (const float*)d_in[14];
    const float* reg_b1 = (const float*)d_in[15];
    const float* reg_w2 = (const float*)d_in[16];
    const float* reg_b2 = (const float*)d_in[17];
    const float* cls_w1 = (const float*)d_in[18];
    const float* cls_b1 = (const float*)d_in[19];
    const float* cls_w2 = (const float*)d_in[20];
    const float* cls_b2 = (const float*)d_in[21];

    char* ws = (char*)d_ws;
    size_t off = 0;
    auto alloc = [&](size_t bytes) { size_t cur = off; off += (bytes + 255) & ~(size_t)255; return cur; };

    ushort_t* xb  = (ushort_t*)(ws + alloc((size_t)16777216 * 2));
    ushort_t* wqT = (ushort_t*)(ws + alloc((size_t)1048576 * 2));
    ushort_t* wkT = (ushort_t*)(ws + alloc((size_t)1048576 * 2));
    ushort_t* Qb  = (ushort_t*)(ws + alloc((size_t)16777216 * 2));
    ushort_t* Kb  = (ushort_t*)(ws + alloc((size_t)16777216 * 2));
    size_t zero_beg = off;
    float* wcol = (float*)(ws + alloc((size_t)131072 * 4));
    float* cm   = (float*)(ws + alloc((size_t)16384 * 4));
    float* gbuf = (float*)(ws + alloc((size_t)16384 * 4));
    float* Ge   = (float*)(ws + alloc((size_t)16384 * 4));
    float* Ee   = (float*)(ws + alloc((size_t)65536 * 4));
    size_t zero_end = off;
    float* u    = (float*)(ws + alloc((size_t)131072 * 4));   // fully overwritten, no memset
    float* DR   = (float*)(ws + alloc((size_t)1048576 * 4));  // fully overwritten

    hipMemsetAsync(ws + zero_beg, 0, zero_end - zero_beg, stream);

    prep_tr_kernel<<<8832, 256, 0, stream>>>(x, xb, wq, wk, wqT, wkT, emb, rg_w1, Ee);
    gemm_qk_kernel<<<dim3(128, 8), 512, 0, stream>>>(xb, wqT, wkT, bq, bk, Qb, Kb);
    attn_mfma_kernel<<<dim3(128, 4), 512, 0, stream>>>(Qb, Kb, wcol);
    u_kernel<<<dim3(16, 16), 256, 0, stream>>>(xb, wcol, u);
    sgemm_kernel<<<dim3(8, 2, 8), 256, 0, stream>>>(u, 8192, 1024, wv, 1024, 128, bv, 128,
                                                    cm, 1024, 128, 16, 128, 1024, 1.f / 1024.f, 8);
    sgemm_kernel<<<dim3(8, 16, 1), 256, 0, stream>>>(cm, 1024, 0, wo, 1024, 0, bo, 0,
                                                     gbuf, 1024, 0, 16, 1024, 1024, 1.f, 8);
    sgemm_kernel<<<dim3(8, 16, 1), 256, 0, stream>>>(gbuf, 1024, 0, rg_w1, 1024, 0, nullptr, 0,
                                                     Ge, 1024, 0, 16, 1024, 1024, 1.f, 8);
    gate_kernel<<<256, 256, 0, stream>>>(Ge, Ee, rg_b1, rg_w2, rg_b2, emb, DR);
    heads_kernel<<<dim3(64, 2, 4), 256, 0, stream>>>(gbuf, DR, reg_w1, cls_w1,
                                                     reg_b1, reg_w2, reg_b2,
                                                     cls_b1, cls_w2, cls_b2, (float*)d_out);
    (void)in_sizes; (void)n_in; (void)out_size; (void)ws_size;
}